// Round 7
// baseline (1668.556 us; speedup 1.0000x reference)
//
#include <hip/hip_runtime.h>
#include <hip/hip_fp16.h>

#define NN 50000
#define NG 256
#define CF 108
#define MD 88
#define OD 100
#define F2 44    // half2 per 88-feat row
#define HP 96    // h row stride in halfs (88 + 8 zero pad, MFMA K=96)
#define HP2 48   // h row stride in half2
#define K1P 128  // layer-1 K padded (108 -> 128)
#define BCAP 1024  // per-sub-bucket record capacity (avg load 512)

typedef _Float16 f16x8 __attribute__((ext_vector_type(8)));
typedef float f32x4 __attribute__((ext_vector_type(4)));

// ---------------- bucket record build ----------------
// bucket b = dst>>6 holds records (src<<6 | dst&63) in region [b*2048, b*2048+2048)
// split into two sub-buckets (by e&1) to halve per-counter atomic chains.

__global__ void bfill_kernel(const int* __restrict__ edge, int E,
                             int* __restrict__ bcur, unsigned* __restrict__ brec) {
    int e = blockIdx.x * blockDim.x + threadIdx.x;
    if (e >= E) return;
    int dst = edge[E + e], src = edge[e];
    int b = dst >> 6, sub = e & 1;
    int pos = atomicAdd(&bcur[b * 2 + sub], 1);
    if (pos < BCAP)
        brec[(size_t)b * (2 * BCAP) + sub * BCAP + pos] =
            ((unsigned)src << 6) | (unsigned)(dst & 63);
}

// ---------------- x -> f16 padded [N][128] ----------------

__global__ void convx_kernel(const float* __restrict__ x, _Float16* __restrict__ xh, int N) {
    int i = blockIdx.x * blockDim.x + threadIdx.x;
    if (i >= N * K1P) return;
    int n = i >> 7, k = i & (K1P - 1);
    xh[i] = (k < CF) ? (_Float16)x[n * CF + k] : (_Float16)0.f;
}

// ---------------- transposed combined weights: Wct[176][KPAD] f16 ----------------

__global__ void build_wct_kernel(const float* __restrict__ Wl, const float* __restrict__ Wr,
                                 _Float16* __restrict__ Wct, int K, int KPAD) {
    int idx = blockIdx.x * blockDim.x + threadIdx.x;
    if (idx >= 176 * KPAD) return;
    int c = idx / KPAD, k = idx - c * KPAD;
    float v = 0.f;
    if (k < K) v = (c < MD) ? Wl[k * MD + c] : Wr[k * MD + (c - MD)];
    Wct[idx] = (_Float16)v;
}

// ---------------- MFMA GEMM: yl[N,88] / yr[N,88] (f16) = A[N,KPAD] @ Wct^T ----------------
// block = 256 = 4 independent waves; wave: 16 rows x 176 cols (11 tiles of 16x16)

template <int KPAD>
__global__ __launch_bounds__(256) void gemm_mfma_kernel(const _Float16* __restrict__ Ah,
                                                        const _Float16* __restrict__ Wct,
                                                        const float* __restrict__ bias,
                                                        _Float16* __restrict__ yl,
                                                        _Float16* __restrict__ yr, int N) {
    const int wave = threadIdx.x >> 6;
    const int lane = threadIdx.x & 63;
    const int r16  = lane & 15;
    const int kg   = lane >> 4;
    const int rbase = blockIdx.x * 64 + wave * 16;

    const int arow = min(rbase + r16, N - 1);
    const _Float16* ap = Ah + (size_t)arow * KPAD + kg * 8;

    f32x4 acc[11];
    #pragma unroll
    for (int t = 0; t < 11; ++t) acc[t] = (f32x4){0.f, 0.f, 0.f, 0.f};

    #pragma unroll
    for (int ks = 0; ks < KPAD / 32; ++ks) {
        f16x8 af = *(const f16x8*)(ap + ks * 32);
        #pragma unroll
        for (int t = 0; t < 11; ++t) {
            const _Float16* bp = Wct + (size_t)(t * 16 + r16) * KPAD + ks * 32 + kg * 8;
            f16x8 bf = *(const f16x8*)bp;
            acc[t] = __builtin_amdgcn_mfma_f32_16x16x32_f16(af, bf, acc[t], 0, 0, 0);
        }
    }

    const int orow0 = rbase + kg * 4;
    #pragma unroll
    for (int t = 0; t < 11; ++t) {
        const int c = t * 16 + r16;
        const bool isr = (c >= MD);
        const float bv = isr ? bias[c - MD] : 0.f;
        _Float16* dst = isr ? (yr + (c - MD)) : (yl + c);
        #pragma unroll
        for (int r = 0; r < 4; ++r) {
            const int row = orow0 + r;
            if (row < N) dst[(size_t)row * MD] = (_Float16)(acc[t][r] + bv);
        }
    }
}

// ---------------- bucket aggregate: LDS fp32 acc per 64-node bucket ----------------
// h[n] = relu( (sum_{src->n} yl[src]) / max(deg,1) + yr[n] ), emitted as f16 [N][96]

__global__ __launch_bounds__(256) void agg_bucket_kernel(const __half2* __restrict__ yl2,
                                                         const __half2* __restrict__ yr2,
                                                         const unsigned* __restrict__ brec,
                                                         const int* __restrict__ bcur,
                                                         __half2* __restrict__ h2, int N) {
    __shared__ float acc[64][MD];   // 22.5 KiB
    __shared__ int ldeg[64];
    const int b    = blockIdx.x;
    const int tid  = threadIdx.x;
    const int w    = tid >> 6;
    const int lane = tid & 63;
    const int nb0  = b * 64;

    for (int i = tid; i < 64 * MD; i += 256) ((float*)acc)[i] = 0.f;
    if (tid < 64) ldeg[tid] = 0;
    __syncthreads();

    #pragma unroll
    for (int seg = 0; seg < 2; ++seg) {
        const int cnt = min(bcur[b * 2 + seg], BCAP);
        const unsigned* rec = brec + (size_t)b * (2 * BCAP) + seg * BCAP;
        for (int r = w; r < cnt; r += 4) {
            const unsigned u = rec[r];
            const int dl  = (int)(u & 63u);
            const int src = (int)(u >> 6);
            if (lane == 0) atomicAdd(&ldeg[dl], 1);
            if (lane < F2) {
                __half2 v = yl2[(size_t)src * F2 + lane];
                atomicAdd(&acc[dl][2 * lane],     __low2float(v));
                atomicAdd(&acc[dl][2 * lane + 1], __high2float(v));
            }
        }
    }
    __syncthreads();

    for (int i = tid; i < 64 * HP2; i += 256) {
        const int n  = i / HP2;
        const int fp = i - n * HP2;
        const int row = nb0 + n;
        if (row >= N) continue;
        __half2 o;
        if (fp < F2) {
            const float inv = 1.f / (float)max(ldeg[n], 1);
            const __half2 r2 = yr2[(size_t)row * F2 + fp];
            const float ox = fmaxf(acc[n][2 * fp]     * inv + __low2float(r2), 0.f);
            const float oy = fmaxf(acc[n][2 * fp + 1] * inv + __high2float(r2), 0.f);
            o = __floats2half2_rn(ox, oy);
        } else {
            o = __floats2half2_rn(0.f, 0.f);
        }
        h2[(size_t)row * HP2 + fp] = o;
    }
}

// ---------------- pooling ----------------

__global__ void gstarts_kernel(const int* __restrict__ batch, int* __restrict__ gstart, int n) {
    int i = blockIdx.x * blockDim.x + threadIdx.x;
    if (i >= n) return;
    int b = batch[i];
    int prev = (i == 0) ? -1 : batch[i - 1];
    for (int g = prev + 1; g <= b; ++g) gstart[g] = i;
    if (i == n - 1) {
        for (int g = b + 1; g <= NG; ++g) gstart[g] = n;
    }
}

// block per graph; 4 waves stride nodes; lanes 0..43 hold a half2 feature pair
__global__ __launch_bounds__(256) void pool_kernel(const __half2* __restrict__ h2,
                                                   const int* __restrict__ gstart,
                                                   float* __restrict__ pooled) {
    __shared__ float red[4][F2][2];
    const int g    = blockIdx.x;
    const int w    = threadIdx.x >> 6;
    const int lane = threadIdx.x & 63;
    const int s = gstart[g], e = gstart[g + 1];

    float ax0 = 0.f, ay0 = 0.f, ax1 = 0.f, ay1 = 0.f;
    if (lane < F2) {
        int n = s + w;
        for (; n + 4 < e; n += 8) {
            __half2 v0 = h2[(size_t)n * HP2 + lane];
            __half2 v1 = h2[(size_t)(n + 4) * HP2 + lane];
            ax0 += __low2float(v0); ay0 += __high2float(v0);
            ax1 += __low2float(v1); ay1 += __high2float(v1);
        }
        if (n < e) {
            __half2 v0 = h2[(size_t)n * HP2 + lane];
            ax0 += __low2float(v0); ay0 += __high2float(v0);
        }
        red[w][lane][0] = ax0 + ax1;
        red[w][lane][1] = ay0 + ay1;
    }
    __syncthreads();
    if (threadIdx.x < F2) {
        const int fp = threadIdx.x;
        float sx = red[0][fp][0] + red[1][fp][0] + red[2][fp][0] + red[3][fp][0];
        float sy = red[0][fp][1] + red[1][fp][1] + red[2][fp][1] + red[3][fp][1];
        float2* pp = (float2*)(pooled + (size_t)g * MD);
        pp[fp] = make_float2(sx, sy);
    }
}

__global__ void final_kernel(const float* __restrict__ pooled, const float* __restrict__ Wlin,
                             const float* __restrict__ blin, float* __restrict__ out) {
    int idx = blockIdx.x * blockDim.x + threadIdx.x;
    if (idx >= NG * OD) return;
    int g = idx / OD, o = idx - (idx / OD) * OD;
    float acc = blin[o];
    for (int f = 0; f < MD; ++f)
        acc = fmaf(pooled[g * MD + f], Wlin[f * OD + o], acc);
    out[idx] = acc;
}

// ---------------- launch ----------------

extern "C" void kernel_launch(void* const* d_in, const int* in_sizes, int n_in,
                              void* d_out, int out_size, void* d_ws, size_t ws_size,
                              hipStream_t stream) {
    const float* x     = (const float*)d_in[0];
    const int*   edge  = (const int*)d_in[1];
    const int*   batch = (const int*)d_in[2];
    const float* W1l = (const float*)d_in[3];
    const float* W1r = (const float*)d_in[4];
    const float* b1  = (const float*)d_in[5];
    const float* W2l = (const float*)d_in[6];
    const float* W2r = (const float*)d_in[7];
    const float* b2  = (const float*)d_in[8];
    const float* W3l = (const float*)d_in[9];
    const float* W3r = (const float*)d_in[10];
    const float* b3  = (const float*)d_in[11];
    const float* Wlin = (const float*)d_in[12];
    const float* blin = (const float*)d_in[13];
    float* out = (float*)d_out;

    const int N = in_sizes[0] / CF;     // 50000
    const int E = in_sizes[1] / 2;      // 800000
    const int NBUK = (N + 63) / 64;     // 782 buckets

    char* ws = (char*)d_ws;
    auto alloc = [&](size_t bytes) -> void* {
        void* p = (void*)ws;
        ws += (bytes + 255) & ~(size_t)255;
        return p;
    };
    int*       bcur    = (int*)alloc((size_t)NBUK * 2 * 4);
    unsigned*  brec    = (unsigned*)alloc((size_t)NBUK * 2 * BCAP * 4);
    int*       gstart  = (int*)alloc((size_t)(NG + 1) * 4);
    _Float16*  Wct     = (_Float16*)alloc((size_t)176 * K1P * 2);
    _Float16*  xh      = (_Float16*)alloc((size_t)N * K1P * 2);
    _Float16*  yl      = (_Float16*)alloc((size_t)N * MD * 2);
    _Float16*  yr      = (_Float16*)alloc((size_t)N * MD * 2);
    _Float16*  h       = (_Float16*)alloc((size_t)N * HP * 2);
    float*     pooled  = (float*)alloc((size_t)NG * MD * 4);

    hipMemsetAsync(bcur, 0, (size_t)NBUK * 2 * 4, stream);
    bfill_kernel<<<(E + 255) / 256, 256, 0, stream>>>(edge, E, bcur, brec);

    convx_kernel<<<(N * K1P + 255) / 256, 256, 0, stream>>>(x, xh, N);

    const int gemm_blocks = (N + 63) / 64;

    // layer 1 (K=108, KPAD=128)
    build_wct_kernel<<<(176 * K1P + 255) / 256, 256, 0, stream>>>(W1l, W1r, Wct, CF, K1P);
    gemm_mfma_kernel<K1P><<<gemm_blocks, 256, 0, stream>>>(xh, Wct, b1, yl, yr, N);
    agg_bucket_kernel<<<NBUK, 256, 0, stream>>>((const __half2*)yl, (const __half2*)yr,
                                                brec, bcur, (__half2*)h, N);

    // layer 2 (K=88, KPAD=96)
    build_wct_kernel<<<(176 * HP + 255) / 256, 256, 0, stream>>>(W2l, W2r, Wct, MD, HP);
    gemm_mfma_kernel<HP><<<gemm_blocks, 256, 0, stream>>>(h, Wct, b2, yl, yr, N);
    agg_bucket_kernel<<<NBUK, 256, 0, stream>>>((const __half2*)yl, (const __half2*)yr,
                                                brec, bcur, (__half2*)h, N);

    // layer 3 (K=88, KPAD=96)
    build_wct_kernel<<<(176 * HP + 255) / 256, 256, 0, stream>>>(W3l, W3r, Wct, MD, HP);
    gemm_mfma_kernel<HP><<<gemm_blocks, 256, 0, stream>>>(h, Wct, b3, yl, yr, N);
    agg_bucket_kernel<<<NBUK, 256, 0, stream>>>((const __half2*)yl, (const __half2*)yr,
                                                brec, bcur, (__half2*)h, N);

    // pool + classifier
    gstarts_kernel<<<(N + 255) / 256, 256, 0, stream>>>(batch, gstart, N);
    pool_kernel<<<NG, 256, 0, stream>>>((const __half2*)h, gstart, pooled);
    final_kernel<<<(NG * OD + 255) / 256, 256, 0, stream>>>(pooled, Wlin, blin, out);
}

// Round 8
// 296.429 us; speedup vs baseline: 5.6289x; 5.6289x over previous
//
#include <hip/hip_runtime.h>
#include <hip/hip_fp16.h>

#define NN 50000
#define NG 256
#define CF 108
#define MD 88
#define OD 100
#define F2 44    // half2 per 88-feat row
#define HP 96    // h row stride in halfs (88 + 8 zero pad, MFMA K=96)
#define HP2 48   // h row stride in half2
#define K1P 128  // layer-1 K padded (108 -> 128)
#define NSUB 4
#define BCAP 512   // per-sub-bucket capacity (avg load 256)
#define BREG (NSUB * BCAP)  // 2048 csr slots per bucket

typedef _Float16 f16x8 __attribute__((ext_vector_type(8)));
typedef float f32x4 __attribute__((ext_vector_type(4)));

// ---------------- bucket record build (dense L2-resident writes) ----------------

__global__ void bfill_kernel(const int* __restrict__ edge, int E,
                             int* __restrict__ bcur, unsigned* __restrict__ brec) {
    int e = blockIdx.x * blockDim.x + threadIdx.x;
    if (e >= E) return;
    int dst = edge[E + e], src = edge[e];
    int b = dst >> 6, sub = e & (NSUB - 1);
    int pos = atomicAdd(&bcur[b * NSUB + sub], 1);
    if (pos < BCAP)
        brec[((size_t)b * NSUB + sub) * BCAP + pos] =
            ((unsigned)src << 6) | (unsigned)(dst & 63);
}

// ---------------- per-bucket CSR: contiguous region, no global scan ----------------

__global__ __launch_bounds__(256) void csr_local_kernel(const unsigned* __restrict__ brec,
                                                        const int* __restrict__ bcur,
                                                        int* __restrict__ csr,
                                                        int2* __restrict__ off2, int N) {
    __shared__ int hist[64], offc[64], base[64];
    const int b = blockIdx.x, tid = threadIdx.x;
    if (tid < 64) hist[tid] = 0;
    __syncthreads();

    #pragma unroll
    for (int s = 0; s < NSUB; ++s) {
        const int cnt = min(bcur[b * NSUB + s], BCAP);
        const unsigned* rec = brec + ((size_t)b * NSUB + s) * BCAP;
        for (int r = tid; r < cnt; r += 256) atomicAdd(&hist[rec[r] & 63u], 1);
    }
    __syncthreads();

    if (tid < 64) {
        int v = hist[tid];
        int incl = v;
        #pragma unroll
        for (int sh = 1; sh < 64; sh <<= 1) {
            int t = __shfl_up(incl, sh, 64);
            if (tid >= sh) incl += t;
        }
        base[tid] = incl - v;
        offc[tid] = incl - v;
    }
    __syncthreads();

    #pragma unroll
    for (int s = 0; s < NSUB; ++s) {
        const int cnt = min(bcur[b * NSUB + s], BCAP);
        const unsigned* rec = brec + ((size_t)b * NSUB + s) * BCAP;
        for (int r = tid; r < cnt; r += 256) {
            unsigned u = rec[r];
            int dl = (int)(u & 63u);
            int pos = atomicAdd(&offc[dl], 1);
            csr[(size_t)b * BREG + pos] = (int)(u >> 6);
        }
    }
    __syncthreads();

    if (tid < 64) {
        int n = b * 64 + tid;
        if (n < N) off2[n] = make_int2(b * BREG + base[tid], hist[tid]);
    }
}

// ---------------- x -> f16 padded [N][128] ----------------

__global__ void convx_kernel(const float* __restrict__ x, _Float16* __restrict__ xh, int N) {
    int i = blockIdx.x * blockDim.x + threadIdx.x;
    if (i >= N * K1P) return;
    int n = i >> 7, k = i & (K1P - 1);
    xh[i] = (k < CF) ? (_Float16)x[n * CF + k] : (_Float16)0.f;
}

// ---------------- transposed combined weights: Wct[176][KPAD] f16 ----------------

__global__ void build_wct_kernel(const float* __restrict__ Wl, const float* __restrict__ Wr,
                                 _Float16* __restrict__ Wct, int K, int KPAD) {
    int idx = blockIdx.x * blockDim.x + threadIdx.x;
    if (idx >= 176 * KPAD) return;
    int c = idx / KPAD, k = idx - c * KPAD;
    float v = 0.f;
    if (k < K) v = (c < MD) ? Wl[k * MD + c] : Wr[k * MD + (c - MD)];
    Wct[idx] = (_Float16)v;
}

// ---------------- MFMA GEMM: yl[N,88] / yr[N,88] (f16) = A[N,KPAD] @ Wct^T ----------------

template <int KPAD>
__global__ __launch_bounds__(256) void gemm_mfma_kernel(const _Float16* __restrict__ Ah,
                                                        const _Float16* __restrict__ Wct,
                                                        const float* __restrict__ bias,
                                                        _Float16* __restrict__ yl,
                                                        _Float16* __restrict__ yr, int N) {
    const int wave = threadIdx.x >> 6;
    const int lane = threadIdx.x & 63;
    const int r16  = lane & 15;
    const int kg   = lane >> 4;
    const int rbase = blockIdx.x * 64 + wave * 16;

    const int arow = min(rbase + r16, N - 1);
    const _Float16* ap = Ah + (size_t)arow * KPAD + kg * 8;

    f32x4 acc[11];
    #pragma unroll
    for (int t = 0; t < 11; ++t) acc[t] = (f32x4){0.f, 0.f, 0.f, 0.f};

    #pragma unroll
    for (int ks = 0; ks < KPAD / 32; ++ks) {
        f16x8 af = *(const f16x8*)(ap + ks * 32);
        #pragma unroll
        for (int t = 0; t < 11; ++t) {
            const _Float16* bp = Wct + (size_t)(t * 16 + r16) * KPAD + ks * 32 + kg * 8;
            f16x8 bf = *(const f16x8*)bp;
            acc[t] = __builtin_amdgcn_mfma_f32_16x16x32_f16(af, bf, acc[t], 0, 0, 0);
        }
    }

    const int orow0 = rbase + kg * 4;
    #pragma unroll
    for (int t = 0; t < 11; ++t) {
        const int c = t * 16 + r16;
        const bool isr = (c >= MD);
        const float bv = isr ? bias[c - MD] : 0.f;
        _Float16* dst = isr ? (yr + (c - MD)) : (yl + c);
        #pragma unroll
        for (int r = 0; r < 4; ++r) {
            const int row = orow0 + r;
            if (row < N) dst[(size_t)row * MD] = (_Float16)(acc[t][r] + bv);
        }
    }
}

// ---------------- fused aggregate (4-way MLP gather) -> h f16 [N][96] ----------------

__global__ void agg_kernel(const __half2* __restrict__ yl2, const __half2* __restrict__ yr2,
                           const int2* __restrict__ off2, const int* __restrict__ csr,
                           __half2* __restrict__ h2, int N) {
    int idx = blockIdx.x * blockDim.x + threadIdx.x;
    if (idx >= N * HP2) return;
    int n  = idx / HP2;
    int fp = idx - n * HP2;
    if (fp >= F2) { h2[idx] = __floats2half2_rn(0.f, 0.f); return; }
    const int2 o = off2[n];
    const int s = o.x, e = o.x + o.y;
    float ax0 = 0.f, ay0 = 0.f, ax1 = 0.f, ay1 = 0.f;
    float ax2 = 0.f, ay2 = 0.f, ax3 = 0.f, ay3 = 0.f;
    int i = s;
    for (; i + 3 < e; i += 4) {
        __half2 v0 = yl2[(size_t)csr[i]     * F2 + fp];
        __half2 v1 = yl2[(size_t)csr[i + 1] * F2 + fp];
        __half2 v2 = yl2[(size_t)csr[i + 2] * F2 + fp];
        __half2 v3 = yl2[(size_t)csr[i + 3] * F2 + fp];
        ax0 += __low2float(v0); ay0 += __high2float(v0);
        ax1 += __low2float(v1); ay1 += __high2float(v1);
        ax2 += __low2float(v2); ay2 += __high2float(v2);
        ax3 += __low2float(v3); ay3 += __high2float(v3);
    }
    for (; i < e; ++i) {
        __half2 v0 = yl2[(size_t)csr[i] * F2 + fp];
        ax0 += __low2float(v0); ay0 += __high2float(v0);
    }
    const float inv = 1.0f / (float)max(o.y, 1);
    const __half2 r2 = yr2[(size_t)n * F2 + fp];
    float ox = fmaxf((ax0 + ax1 + ax2 + ax3) * inv + __low2float(r2), 0.f);
    float oy = fmaxf((ay0 + ay1 + ay2 + ay3) * inv + __high2float(r2), 0.f);
    h2[idx] = __floats2half2_rn(ox, oy);
}

// ---------------- pooling ----------------

__global__ void gstarts_kernel(const int* __restrict__ batch, int* __restrict__ gstart, int n) {
    int i = blockIdx.x * blockDim.x + threadIdx.x;
    if (i >= n) return;
    int b = batch[i];
    int prev = (i == 0) ? -1 : batch[i - 1];
    for (int g = prev + 1; g <= b; ++g) gstart[g] = i;
    if (i == n - 1) {
        for (int g = b + 1; g <= NG; ++g) gstart[g] = n;
    }
}

__global__ __launch_bounds__(256) void pool_kernel(const __half2* __restrict__ h2,
                                                   const int* __restrict__ gstart,
                                                   float* __restrict__ pooled) {
    __shared__ float red[4][F2][2];
    const int g    = blockIdx.x;
    const int w    = threadIdx.x >> 6;
    const int lane = threadIdx.x & 63;
    const int s = gstart[g], e = gstart[g + 1];

    float ax0 = 0.f, ay0 = 0.f, ax1 = 0.f, ay1 = 0.f;
    if (lane < F2) {
        int n = s + w;
        for (; n + 4 < e; n += 8) {
            __half2 v0 = h2[(size_t)n * HP2 + lane];
            __half2 v1 = h2[(size_t)(n + 4) * HP2 + lane];
            ax0 += __low2float(v0); ay0 += __high2float(v0);
            ax1 += __low2float(v1); ay1 += __high2float(v1);
        }
        if (n < e) {
            __half2 v0 = h2[(size_t)n * HP2 + lane];
            ax0 += __low2float(v0); ay0 += __high2float(v0);
        }
        red[w][lane][0] = ax0 + ax1;
        red[w][lane][1] = ay0 + ay1;
    }
    __syncthreads();
    if (threadIdx.x < F2) {
        const int fp = threadIdx.x;
        float sx = red[0][fp][0] + red[1][fp][0] + red[2][fp][0] + red[3][fp][0];
        float sy = red[0][fp][1] + red[1][fp][1] + red[2][fp][1] + red[3][fp][1];
        float2* pp = (float2*)(pooled + (size_t)g * MD);
        pp[fp] = make_float2(sx, sy);
    }
}

__global__ void final_kernel(const float* __restrict__ pooled, const float* __restrict__ Wlin,
                             const float* __restrict__ blin, float* __restrict__ out) {
    int idx = blockIdx.x * blockDim.x + threadIdx.x;
    if (idx >= NG * OD) return;
    int g = idx / OD, o = idx - (idx / OD) * OD;
    float acc = blin[o];
    for (int f = 0; f < MD; ++f)
        acc = fmaf(pooled[g * MD + f], Wlin[f * OD + o], acc);
    out[idx] = acc;
}

// ---------------- launch ----------------

extern "C" void kernel_launch(void* const* d_in, const int* in_sizes, int n_in,
                              void* d_out, int out_size, void* d_ws, size_t ws_size,
                              hipStream_t stream) {
    const float* x     = (const float*)d_in[0];
    const int*   edge  = (const int*)d_in[1];
    const int*   batch = (const int*)d_in[2];
    const float* W1l = (const float*)d_in[3];
    const float* W1r = (const float*)d_in[4];
    const float* b1  = (const float*)d_in[5];
    const float* W2l = (const float*)d_in[6];
    const float* W2r = (const float*)d_in[7];
    const float* b2  = (const float*)d_in[8];
    const float* W3l = (const float*)d_in[9];
    const float* W3r = (const float*)d_in[10];
    const float* b3  = (const float*)d_in[11];
    const float* Wlin = (const float*)d_in[12];
    const float* blin = (const float*)d_in[13];
    float* out = (float*)d_out;

    const int N = in_sizes[0] / CF;     // 50000
    const int E = in_sizes[1] / 2;      // 800000
    const int NBUK = (N + 63) / 64;     // 782 buckets

    char* ws = (char*)d_ws;
    auto alloc = [&](size_t bytes) -> void* {
        void* p = (void*)ws;
        ws += (bytes + 255) & ~(size_t)255;
        return p;
    };
    int*       bcur    = (int*)alloc((size_t)NBUK * NSUB * 4);
    unsigned*  brec    = (unsigned*)alloc((size_t)NBUK * BREG * 4);
    int*       csr     = (int*)alloc((size_t)NBUK * BREG * 4);
    int2*      off2    = (int2*)alloc((size_t)N * 8);
    int*       gstart  = (int*)alloc((size_t)(NG + 1) * 4);
    _Float16*  Wct     = (_Float16*)alloc((size_t)176 * K1P * 2);
    _Float16*  xh      = (_Float16*)alloc((size_t)N * K1P * 2);
    _Float16*  yl      = (_Float16*)alloc((size_t)N * MD * 2);
    _Float16*  yr      = (_Float16*)alloc((size_t)N * MD * 2);
    _Float16*  h       = (_Float16*)alloc((size_t)N * HP * 2);
    float*     pooled  = (float*)alloc((size_t)NG * MD * 4);

    hipMemsetAsync(bcur, 0, (size_t)NBUK * NSUB * 4, stream);
    bfill_kernel<<<(E + 255) / 256, 256, 0, stream>>>(edge, E, bcur, brec);
    csr_local_kernel<<<NBUK, 256, 0, stream>>>(brec, bcur, csr, off2, N);

    convx_kernel<<<(N * K1P + 255) / 256, 256, 0, stream>>>(x, xh, N);

    const int gemm_blocks = (N + 63) / 64;
    const int agg_blocks  = (N * HP2 + 255) / 256;

    // layer 1 (K=108, KPAD=128)
    build_wct_kernel<<<(176 * K1P + 255) / 256, 256, 0, stream>>>(W1l, W1r, Wct, CF, K1P);
    gemm_mfma_kernel<K1P><<<gemm_blocks, 256, 0, stream>>>(xh, Wct, b1, yl, yr, N);
    agg_kernel<<<agg_blocks, 256, 0, stream>>>((const __half2*)yl, (const __half2*)yr,
                                               off2, csr, (__half2*)h, N);

    // layer 2 (K=88, KPAD=96)
    build_wct_kernel<<<(176 * HP + 255) / 256, 256, 0, stream>>>(W2l, W2r, Wct, MD, HP);
    gemm_mfma_kernel<HP><<<gemm_blocks, 256, 0, stream>>>(h, Wct, b2, yl, yr, N);
    agg_kernel<<<agg_blocks, 256, 0, stream>>>((const __half2*)yl, (const __half2*)yr,
                                               off2, csr, (__half2*)h, N);

    // layer 3 (K=88, KPAD=96)
    build_wct_kernel<<<(176 * HP + 255) / 256, 256, 0, stream>>>(W3l, W3r, Wct, MD, HP);
    gemm_mfma_kernel<HP><<<gemm_blocks, 256, 0, stream>>>(h, Wct, b3, yl, yr, N);
    agg_kernel<<<agg_blocks, 256, 0, stream>>>((const __half2*)yl, (const __half2*)yr,
                                               off2, csr, (__half2*)h, N);

    // pool + classifier
    gstarts_kernel<<<(N + 255) / 256, 256, 0, stream>>>(batch, gstart, N);
    pool_kernel<<<NG, 256, 0, stream>>>((const __half2*)h, gstart, pooled);
    final_kernel<<<(NG * OD + 255) / 256, 256, 0, stream>>>(pooled, Wlin, blin, out);
}

// Round 9
// 242.604 us; speedup vs baseline: 6.8777x; 1.2219x over previous
//
#include <hip/hip_runtime.h>
#include <hip/hip_fp16.h>

#define NN 50000
#define NG 256
#define CF 108
#define MD 88
#define OD 100
#define F2 44    // half2 per 88-feat row
#define HP 96    // h row stride in halfs (88 + 8 zero pad, MFMA K=96)
#define HP2 48   // h row stride in half2
#define K1P 128  // layer-1 K padded (108 -> 128)
#define NSB 196      // super-buckets of 256 nodes
#define SBCAP 5120   // records per super-bucket (avg 4096)
#define TILE 4096    // edges per bin_kernel block

typedef _Float16 f16x8 __attribute__((ext_vector_type(8)));
typedef float f32x4 __attribute__((ext_vector_type(4)));

// ---------------- phase A: LDS-staged binning (dense chunk writes) ----------------
// record = (src<<8) | (dst & 255), bin = dst>>8

__global__ __launch_bounds__(256) void bin_kernel(const int* __restrict__ edge, int E,
                                                  int* __restrict__ sbcur,
                                                  unsigned* __restrict__ sbrec) {
    __shared__ int bcnt[NSB], boff[NSB], bfill[NSB], gbase[NSB];
    __shared__ int sc[256];
    __shared__ unsigned stag[TILE];
    __shared__ unsigned char stagbin[TILE];
    const int tid = threadIdx.x;
    const int t0  = blockIdx.x * TILE;
    const int tcnt = min(TILE, E - t0);

    for (int i = tid; i < NSB; i += 256) bcnt[i] = 0;
    __syncthreads();

    unsigned recs[TILE / 256];
    int      bins[TILE / 256];
    #pragma unroll
    for (int j = 0; j < TILE / 256; ++j) {
        const int e = t0 + j * 256 + tid;
        bins[j] = -1;
        if (e < E) {
            const int dst = edge[E + e], src = edge[e];
            bins[j] = dst >> 8;
            recs[j] = ((unsigned)src << 8) | (unsigned)(dst & 255);
            atomicAdd(&bcnt[bins[j]], 1);
        }
    }
    __syncthreads();

    // block scan (Hillis-Steele over 256, NSB<=256)
    sc[tid] = (tid < NSB) ? bcnt[tid] : 0;
    __syncthreads();
    for (int d = 1; d < 256; d <<= 1) {
        int v = (tid >= d) ? sc[tid - d] : 0;
        __syncthreads();
        sc[tid] += v;
        __syncthreads();
    }
    if (tid < NSB) {
        boff[tid]  = sc[tid] - bcnt[tid];
        bfill[tid] = sc[tid] - bcnt[tid];
        if (bcnt[tid] > 0) gbase[tid] = atomicAdd(&sbcur[tid], bcnt[tid]);
    }
    __syncthreads();

    // scatter into LDS staging (ordered by bin)
    #pragma unroll
    for (int j = 0; j < TILE / 256; ++j) {
        if (bins[j] >= 0) {
            int pos = atomicAdd(&bfill[bins[j]], 1);
            stag[pos]    = recs[j];
            stagbin[pos] = (unsigned char)bins[j];
        }
    }
    __syncthreads();

    // dense chunk copy to global per-bin regions
    for (int i = tid; i < tcnt; i += 256) {
        const int b   = stagbin[i];
        const int rel = i - boff[b];
        const int gp  = gbase[b] + rel;
        if (gp < SBCAP) sbrec[(size_t)b * SBCAP + gp] = stag[i];
    }
}

// ---------------- phase B: per-super-bucket CSR ----------------

__global__ __launch_bounds__(256) void csr256_kernel(const unsigned* __restrict__ sbrec,
                                                     const int* __restrict__ sbcur,
                                                     int* __restrict__ csr,
                                                     int2* __restrict__ off2, int N) {
    __shared__ int hist[256], base[256], offc[256], sc[256];
    const int b = blockIdx.x, tid = threadIdx.x;
    const int cnt = min(sbcur[b], SBCAP);
    const unsigned* rec = sbrec + (size_t)b * SBCAP;

    hist[tid] = 0;
    __syncthreads();
    for (int r = tid; r < cnt; r += 256) atomicAdd(&hist[rec[r] & 255u], 1);
    __syncthreads();

    sc[tid] = hist[tid];
    __syncthreads();
    for (int d = 1; d < 256; d <<= 1) {
        int v = (tid >= d) ? sc[tid - d] : 0;
        __syncthreads();
        sc[tid] += v;
        __syncthreads();
    }
    base[tid] = sc[tid] - hist[tid];
    offc[tid] = base[tid];
    __syncthreads();

    for (int r = tid; r < cnt; r += 256) {
        const unsigned u = rec[r];
        const int dl = (int)(u & 255u);
        const int pos = atomicAdd(&offc[dl], 1);
        csr[(size_t)b * SBCAP + pos] = (int)(u >> 8);
    }
    __syncthreads();

    const int n = b * 256 + tid;
    if (n < N) off2[n] = make_int2(b * SBCAP + base[tid], hist[tid]);
}

// ---------------- x -> f16 padded [N][128] ----------------

__global__ void convx_kernel(const float* __restrict__ x, _Float16* __restrict__ xh, int N) {
    int i = blockIdx.x * blockDim.x + threadIdx.x;
    if (i >= N * K1P) return;
    int n = i >> 7, k = i & (K1P - 1);
    xh[i] = (k < CF) ? (_Float16)x[n * CF + k] : (_Float16)0.f;
}

// ---------------- transposed combined weights: Wct[176][KPAD] f16 ----------------

__global__ void build_wct_kernel(const float* __restrict__ Wl, const float* __restrict__ Wr,
                                 _Float16* __restrict__ Wct, int K, int KPAD) {
    int idx = blockIdx.x * blockDim.x + threadIdx.x;
    if (idx >= 176 * KPAD) return;
    int c = idx / KPAD, k = idx - c * KPAD;
    float v = 0.f;
    if (k < K) v = (c < MD) ? Wl[k * MD + c] : Wr[k * MD + (c - MD)];
    Wct[idx] = (_Float16)v;
}

// ---------------- MFMA GEMM: yl[N,88] / yr[N,88] (f16) = A[N,KPAD] @ Wct^T ----------------

template <int KPAD>
__global__ __launch_bounds__(256) void gemm_mfma_kernel(const _Float16* __restrict__ Ah,
                                                        const _Float16* __restrict__ Wct,
                                                        const float* __restrict__ bias,
                                                        _Float16* __restrict__ yl,
                                                        _Float16* __restrict__ yr, int N) {
    const int wave = threadIdx.x >> 6;
    const int lane = threadIdx.x & 63;
    const int r16  = lane & 15;
    const int kg   = lane >> 4;
    const int rbase = blockIdx.x * 64 + wave * 16;

    const int arow = min(rbase + r16, N - 1);
    const _Float16* ap = Ah + (size_t)arow * KPAD + kg * 8;

    f32x4 acc[11];
    #pragma unroll
    for (int t = 0; t < 11; ++t) acc[t] = (f32x4){0.f, 0.f, 0.f, 0.f};

    #pragma unroll
    for (int ks = 0; ks < KPAD / 32; ++ks) {
        f16x8 af = *(const f16x8*)(ap + ks * 32);
        #pragma unroll
        for (int t = 0; t < 11; ++t) {
            const _Float16* bp = Wct + (size_t)(t * 16 + r16) * KPAD + ks * 32 + kg * 8;
            f16x8 bf = *(const f16x8*)bp;
            acc[t] = __builtin_amdgcn_mfma_f32_16x16x32_f16(af, bf, acc[t], 0, 0, 0);
        }
    }

    const int orow0 = rbase + kg * 4;
    #pragma unroll
    for (int t = 0; t < 11; ++t) {
        const int c = t * 16 + r16;
        const bool isr = (c >= MD);
        const float bv = isr ? bias[c - MD] : 0.f;
        _Float16* dst = isr ? (yr + (c - MD)) : (yl + c);
        #pragma unroll
        for (int r = 0; r < 4; ++r) {
            const int row = orow0 + r;
            if (row < N) dst[(size_t)row * MD] = (_Float16)(acc[t][r] + bv);
        }
    }
}

// ---------------- fused aggregate (4-way MLP gather) -> h f16 [N][96] ----------------

__global__ void agg_kernel(const __half2* __restrict__ yl2, const __half2* __restrict__ yr2,
                           const int2* __restrict__ off2, const int* __restrict__ csr,
                           __half2* __restrict__ h2, int N) {
    int idx = blockIdx.x * blockDim.x + threadIdx.x;
    if (idx >= N * HP2) return;
    int n  = idx / HP2;
    int fp = idx - n * HP2;
    if (fp >= F2) { h2[idx] = __floats2half2_rn(0.f, 0.f); return; }
    const int2 o = off2[n];
    const int s = o.x, e = o.x + o.y;
    float ax0 = 0.f, ay0 = 0.f, ax1 = 0.f, ay1 = 0.f;
    float ax2 = 0.f, ay2 = 0.f, ax3 = 0.f, ay3 = 0.f;
    int i = s;
    for (; i + 3 < e; i += 4) {
        __half2 v0 = yl2[(size_t)csr[i]     * F2 + fp];
        __half2 v1 = yl2[(size_t)csr[i + 1] * F2 + fp];
        __half2 v2 = yl2[(size_t)csr[i + 2] * F2 + fp];
        __half2 v3 = yl2[(size_t)csr[i + 3] * F2 + fp];
        ax0 += __low2float(v0); ay0 += __high2float(v0);
        ax1 += __low2float(v1); ay1 += __high2float(v1);
        ax2 += __low2float(v2); ay2 += __high2float(v2);
        ax3 += __low2float(v3); ay3 += __high2float(v3);
    }
    for (; i < e; ++i) {
        __half2 v0 = yl2[(size_t)csr[i] * F2 + fp];
        ax0 += __low2float(v0); ay0 += __high2float(v0);
    }
    const float inv = 1.0f / (float)max(o.y, 1);
    const __half2 r2 = yr2[(size_t)n * F2 + fp];
    float ox = fmaxf((ax0 + ax1 + ax2 + ax3) * inv + __low2float(r2), 0.f);
    float oy = fmaxf((ay0 + ay1 + ay2 + ay3) * inv + __high2float(r2), 0.f);
    h2[idx] = __floats2half2_rn(ox, oy);
}

// ---------------- pooling ----------------

__global__ void gstarts_kernel(const int* __restrict__ batch, int* __restrict__ gstart, int n) {
    int i = blockIdx.x * blockDim.x + threadIdx.x;
    if (i >= n) return;
    int b = batch[i];
    int prev = (i == 0) ? -1 : batch[i - 1];
    for (int g = prev + 1; g <= b; ++g) gstart[g] = i;
    if (i == n - 1) {
        for (int g = b + 1; g <= NG; ++g) gstart[g] = n;
    }
}

__global__ __launch_bounds__(256) void pool_kernel(const __half2* __restrict__ h2,
                                                   const int* __restrict__ gstart,
                                                   float* __restrict__ pooled) {
    __shared__ float red[4][F2][2];
    const int g    = blockIdx.x;
    const int w    = threadIdx.x >> 6;
    const int lane = threadIdx.x & 63;
    const int s = gstart[g], e = gstart[g + 1];

    float ax0 = 0.f, ay0 = 0.f, ax1 = 0.f, ay1 = 0.f;
    if (lane < F2) {
        int n = s + w;
        for (; n + 4 < e; n += 8) {
            __half2 v0 = h2[(size_t)n * HP2 + lane];
            __half2 v1 = h2[(size_t)(n + 4) * HP2 + lane];
            ax0 += __low2float(v0); ay0 += __high2float(v0);
            ax1 += __low2float(v1); ay1 += __high2float(v1);
        }
        if (n < e) {
            __half2 v0 = h2[(size_t)n * HP2 + lane];
            ax0 += __low2float(v0); ay0 += __high2float(v0);
        }
        red[w][lane][0] = ax0 + ax1;
        red[w][lane][1] = ay0 + ay1;
    }
    __syncthreads();
    if (threadIdx.x < F2) {
        const int fp = threadIdx.x;
        float sx = red[0][fp][0] + red[1][fp][0] + red[2][fp][0] + red[3][fp][0];
        float sy = red[0][fp][1] + red[1][fp][1] + red[2][fp][1] + red[3][fp][1];
        float2* pp = (float2*)(pooled + (size_t)g * MD);
        pp[fp] = make_float2(sx, sy);
    }
}

__global__ void final_kernel(const float* __restrict__ pooled, const float* __restrict__ Wlin,
                             const float* __restrict__ blin, float* __restrict__ out) {
    int idx = blockIdx.x * blockDim.x + threadIdx.x;
    if (idx >= NG * OD) return;
    int g = idx / OD, o = idx - (idx / OD) * OD;
    float acc = blin[o];
    for (int f = 0; f < MD; ++f)
        acc = fmaf(pooled[g * MD + f], Wlin[f * OD + o], acc);
    out[idx] = acc;
}

// ---------------- launch ----------------

extern "C" void kernel_launch(void* const* d_in, const int* in_sizes, int n_in,
                              void* d_out, int out_size, void* d_ws, size_t ws_size,
                              hipStream_t stream) {
    const float* x     = (const float*)d_in[0];
    const int*   edge  = (const int*)d_in[1];
    const int*   batch = (const int*)d_in[2];
    const float* W1l = (const float*)d_in[3];
    const float* W1r = (const float*)d_in[4];
    const float* b1  = (const float*)d_in[5];
    const float* W2l = (const float*)d_in[6];
    const float* W2r = (const float*)d_in[7];
    const float* b2  = (const float*)d_in[8];
    const float* W3l = (const float*)d_in[9];
    const float* W3r = (const float*)d_in[10];
    const float* b3  = (const float*)d_in[11];
    const float* Wlin = (const float*)d_in[12];
    const float* blin = (const float*)d_in[13];
    float* out = (float*)d_out;

    const int N = in_sizes[0] / CF;     // 50000
    const int E = in_sizes[1] / 2;      // 800000

    char* ws = (char*)d_ws;
    auto alloc = [&](size_t bytes) -> void* {
        void* p = (void*)ws;
        ws += (bytes + 255) & ~(size_t)255;
        return p;
    };
    int*       sbcur   = (int*)alloc((size_t)NSB * 4);
    unsigned*  sbrec   = (unsigned*)alloc((size_t)NSB * SBCAP * 4);
    int*       csr     = (int*)alloc((size_t)NSB * SBCAP * 4);
    int2*      off2    = (int2*)alloc((size_t)N * 8);
    int*       gstart  = (int*)alloc((size_t)(NG + 1) * 4);
    _Float16*  Wct     = (_Float16*)alloc((size_t)176 * K1P * 2);
    _Float16*  xh      = (_Float16*)alloc((size_t)N * K1P * 2);
    _Float16*  yl      = (_Float16*)alloc((size_t)N * MD * 2);
    _Float16*  yr      = (_Float16*)alloc((size_t)N * MD * 2);
    _Float16*  h       = (_Float16*)alloc((size_t)N * HP * 2);
    float*     pooled  = (float*)alloc((size_t)NG * MD * 4);

    hipMemsetAsync(sbcur, 0, (size_t)NSB * 4, stream);
    bin_kernel<<<(E + TILE - 1) / TILE, 256, 0, stream>>>(edge, E, sbcur, sbrec);
    csr256_kernel<<<NSB, 256, 0, stream>>>(sbrec, sbcur, csr, off2, N);

    convx_kernel<<<(N * K1P + 255) / 256, 256, 0, stream>>>(x, xh, N);

    const int gemm_blocks = (N + 63) / 64;
    const int agg_blocks  = (N * HP2 + 255) / 256;

    // layer 1 (K=108, KPAD=128)
    build_wct_kernel<<<(176 * K1P + 255) / 256, 256, 0, stream>>>(W1l, W1r, Wct, CF, K1P);
    gemm_mfma_kernel<K1P><<<gemm_blocks, 256, 0, stream>>>(xh, Wct, b1, yl, yr, N);
    agg_kernel<<<agg_blocks, 256, 0, stream>>>((const __half2*)yl, (const __half2*)yr,
                                               off2, csr, (__half2*)h, N);

    // layer 2 (K=88, KPAD=96)
    build_wct_kernel<<<(176 * HP + 255) / 256, 256, 0, stream>>>(W2l, W2r, Wct, MD, HP);
    gemm_mfma_kernel<HP><<<gemm_blocks, 256, 0, stream>>>(h, Wct, b2, yl, yr, N);
    agg_kernel<<<agg_blocks, 256, 0, stream>>>((const __half2*)yl, (const __half2*)yr,
                                               off2, csr, (__half2*)h, N);

    // layer 3 (K=88, KPAD=96)
    build_wct_kernel<<<(176 * HP + 255) / 256, 256, 0, stream>>>(W3l, W3r, Wct, MD, HP);
    gemm_mfma_kernel<HP><<<gemm_blocks, 256, 0, stream>>>(h, Wct, b3, yl, yr, N);
    agg_kernel<<<agg_blocks, 256, 0, stream>>>((const __half2*)yl, (const __half2*)yr,
                                               off2, csr, (__half2*)h, N);

    // pool + classifier
    gstarts_kernel<<<(N + 255) / 256, 256, 0, stream>>>(batch, gstart, N);
    pool_kernel<<<NG, 256, 0, stream>>>((const __half2*)h, gstart, pooled);
    final_kernel<<<(NG * OD + 255) / 256, 256, 0, stream>>>(pooled, Wlin, blin, out);
}

// Round 10
// 223.384 us; speedup vs baseline: 7.4694x; 1.0860x over previous
//
#include <hip/hip_runtime.h>
#include <hip/hip_fp16.h>

#define NN 50000
#define NG 256
#define CF 108
#define MD 88
#define OD 100
#define F2 44    // half2 per 88-feat row
#define HP 96    // h row stride in halfs (88 + 8 zero pad, MFMA K=96)
#define HP2 48   // h row stride in half2
#define K1P 128  // layer-1 K padded (108 -> 128)
#define NSB 196      // super-buckets of 256 nodes
#define SBCAP 5120   // records per super-bucket (avg 4096)
#define TILE 4096    // edges per bin_kernel block
#define NCH 12       // 16B chunks per node in agg (11 real + 1 pad)

typedef _Float16 f16x8 __attribute__((ext_vector_type(8)));
typedef float f32x4 __attribute__((ext_vector_type(4)));

// ---------------- phase A: LDS-staged binning (dense chunk writes) ----------------
// record = (src<<8) | (dst & 255), bin = dst>>8

__global__ __launch_bounds__(256) void bin_kernel(const int* __restrict__ edge, int E,
                                                  int* __restrict__ sbcur,
                                                  unsigned* __restrict__ sbrec) {
    __shared__ int bcnt[NSB], boff[NSB], bfill[NSB], gbase[NSB];
    __shared__ int sc[256];
    __shared__ unsigned stag[TILE];
    __shared__ unsigned char stagbin[TILE];
    const int tid = threadIdx.x;
    const int t0  = blockIdx.x * TILE;
    const int tcnt = min(TILE, E - t0);

    for (int i = tid; i < NSB; i += 256) bcnt[i] = 0;
    __syncthreads();

    unsigned recs[TILE / 256];
    int      bins[TILE / 256];
    #pragma unroll
    for (int j = 0; j < TILE / 256; ++j) {
        const int e = t0 + j * 256 + tid;
        bins[j] = -1;
        if (e < E) {
            const int dst = edge[E + e], src = edge[e];
            bins[j] = dst >> 8;
            recs[j] = ((unsigned)src << 8) | (unsigned)(dst & 255);
            atomicAdd(&bcnt[bins[j]], 1);
        }
    }
    __syncthreads();

    sc[tid] = (tid < NSB) ? bcnt[tid] : 0;
    __syncthreads();
    for (int d = 1; d < 256; d <<= 1) {
        int v = (tid >= d) ? sc[tid - d] : 0;
        __syncthreads();
        sc[tid] += v;
        __syncthreads();
    }
    if (tid < NSB) {
        boff[tid]  = sc[tid] - bcnt[tid];
        bfill[tid] = sc[tid] - bcnt[tid];
        if (bcnt[tid] > 0) gbase[tid] = atomicAdd(&sbcur[tid], bcnt[tid]);
    }
    __syncthreads();

    #pragma unroll
    for (int j = 0; j < TILE / 256; ++j) {
        if (bins[j] >= 0) {
            int pos = atomicAdd(&bfill[bins[j]], 1);
            stag[pos]    = recs[j];
            stagbin[pos] = (unsigned char)bins[j];
        }
    }
    __syncthreads();

    for (int i = tid; i < tcnt; i += 256) {
        const int b   = stagbin[i];
        const int rel = i - boff[b];
        const int gp  = gbase[b] + rel;
        if (gp < SBCAP) sbrec[(size_t)b * SBCAP + gp] = stag[i];
    }
}

// ---------------- phase B: per-super-bucket CSR ----------------

__global__ __launch_bounds__(256) void csr256_kernel(const unsigned* __restrict__ sbrec,
                                                     const int* __restrict__ sbcur,
                                                     int* __restrict__ csr,
                                                     int2* __restrict__ off2, int N) {
    __shared__ int hist[256], base[256], offc[256], sc[256];
    const int b = blockIdx.x, tid = threadIdx.x;
    const int cnt = min(sbcur[b], SBCAP);
    const unsigned* rec = sbrec + (size_t)b * SBCAP;

    hist[tid] = 0;
    __syncthreads();
    for (int r = tid; r < cnt; r += 256) atomicAdd(&hist[rec[r] & 255u], 1);
    __syncthreads();

    sc[tid] = hist[tid];
    __syncthreads();
    for (int d = 1; d < 256; d <<= 1) {
        int v = (tid >= d) ? sc[tid - d] : 0;
        __syncthreads();
        sc[tid] += v;
        __syncthreads();
    }
    base[tid] = sc[tid] - hist[tid];
    offc[tid] = base[tid];
    __syncthreads();

    for (int r = tid; r < cnt; r += 256) {
        const unsigned u = rec[r];
        const int dl = (int)(u & 255u);
        const int pos = atomicAdd(&offc[dl], 1);
        csr[(size_t)b * SBCAP + pos] = (int)(u >> 8);
    }
    __syncthreads();

    const int n = b * 256 + tid;
    if (n < N) off2[n] = make_int2(b * SBCAP + base[tid], hist[tid]);
}

// ---------------- x -> f16 padded [N][128] ----------------

__global__ void convx_kernel(const float* __restrict__ x, _Float16* __restrict__ xh, int N) {
    int i = blockIdx.x * blockDim.x + threadIdx.x;
    if (i >= N * K1P) return;
    int n = i >> 7, k = i & (K1P - 1);
    xh[i] = (k < CF) ? (_Float16)x[n * CF + k] : (_Float16)0.f;
}

// ---------------- transposed combined weights: Wct[176][KPAD] f16 ----------------

__global__ void build_wct_kernel(const float* __restrict__ Wl, const float* __restrict__ Wr,
                                 _Float16* __restrict__ Wct, int K, int KPAD) {
    int idx = blockIdx.x * blockDim.x + threadIdx.x;
    if (idx >= 176 * KPAD) return;
    int c = idx / KPAD, k = idx - c * KPAD;
    float v = 0.f;
    if (k < K) v = (c < MD) ? Wl[k * MD + c] : Wr[k * MD + (c - MD)];
    Wct[idx] = (_Float16)v;
}

// ---------------- MFMA GEMM: yl[N,88] / yr[N,88] (f16) = A[N,KPAD] @ Wct^T ----------------

template <int KPAD>
__global__ __launch_bounds__(256) void gemm_mfma_kernel(const _Float16* __restrict__ Ah,
                                                        const _Float16* __restrict__ Wct,
                                                        const float* __restrict__ bias,
                                                        _Float16* __restrict__ yl,
                                                        _Float16* __restrict__ yr, int N) {
    const int wave = threadIdx.x >> 6;
    const int lane = threadIdx.x & 63;
    const int r16  = lane & 15;
    const int kg   = lane >> 4;
    const int rbase = blockIdx.x * 64 + wave * 16;

    const int arow = min(rbase + r16, N - 1);
    const _Float16* ap = Ah + (size_t)arow * KPAD + kg * 8;

    f32x4 acc[11];
    #pragma unroll
    for (int t = 0; t < 11; ++t) acc[t] = (f32x4){0.f, 0.f, 0.f, 0.f};

    #pragma unroll
    for (int ks = 0; ks < KPAD / 32; ++ks) {
        f16x8 af = *(const f16x8*)(ap + ks * 32);
        #pragma unroll
        for (int t = 0; t < 11; ++t) {
            const _Float16* bp = Wct + (size_t)(t * 16 + r16) * KPAD + ks * 32 + kg * 8;
            f16x8 bf = *(const f16x8*)bp;
            acc[t] = __builtin_amdgcn_mfma_f32_16x16x32_f16(af, bf, acc[t], 0, 0, 0);
        }
    }

    const int orow0 = rbase + kg * 4;
    #pragma unroll
    for (int t = 0; t < 11; ++t) {
        const int c = t * 16 + r16;
        const bool isr = (c >= MD);
        const float bv = isr ? bias[c - MD] : 0.f;
        _Float16* dst = isr ? (yr + (c - MD)) : (yl + c);
        #pragma unroll
        for (int r = 0; r < 4; ++r) {
            const int row = orow0 + r;
            if (row < N) dst[(size_t)row * MD] = (_Float16)(acc[t][r] + bv);
        }
    }
}

// ---------------- fused aggregate: 16B gathers, thread per (node, chunk) ----------------
// idx = n*12 + c; c in [0,11): 16B chunk of the 176B row; c==11 writes the 16B pad.

__global__ void agg_kernel(const _Float16* __restrict__ yl, const _Float16* __restrict__ yr,
                           const int2* __restrict__ off2, const int* __restrict__ csr,
                           _Float16* __restrict__ h, int N) {
    int idx = blockIdx.x * blockDim.x + threadIdx.x;
    if (idx >= N * NCH) return;
    int n = idx / NCH;
    int c = idx - n * NCH;
    if (c >= 11) {
        *(f16x8*)(h + (size_t)n * HP + 88) = (f16x8)(_Float16)0.f;
        return;
    }
    const int2 o = off2[n];
    const int s = o.x, e = o.x + o.y;
    float a0[8] = {0,0,0,0,0,0,0,0}, a1[8] = {0,0,0,0,0,0,0,0};
    float a2[8] = {0,0,0,0,0,0,0,0}, a3[8] = {0,0,0,0,0,0,0,0};
    const size_t cof = (size_t)c * 8;
    int i = s;
    for (; i + 3 < e; i += 4) {
        f16x8 v0 = *(const f16x8*)(yl + (size_t)csr[i]     * MD + cof);
        f16x8 v1 = *(const f16x8*)(yl + (size_t)csr[i + 1] * MD + cof);
        f16x8 v2 = *(const f16x8*)(yl + (size_t)csr[i + 2] * MD + cof);
        f16x8 v3 = *(const f16x8*)(yl + (size_t)csr[i + 3] * MD + cof);
        #pragma unroll
        for (int j = 0; j < 8; ++j) {
            a0[j] += (float)v0[j]; a1[j] += (float)v1[j];
            a2[j] += (float)v2[j]; a3[j] += (float)v3[j];
        }
    }
    for (; i < e; ++i) {
        f16x8 v0 = *(const f16x8*)(yl + (size_t)csr[i] * MD + cof);
        #pragma unroll
        for (int j = 0; j < 8; ++j) a0[j] += (float)v0[j];
    }
    const float inv = 1.0f / (float)max(o.y, 1);
    const f16x8 r = *(const f16x8*)(yr + (size_t)n * MD + cof);
    f16x8 outv;
    #pragma unroll
    for (int j = 0; j < 8; ++j) {
        float v = (a0[j] + a1[j] + a2[j] + a3[j]) * inv + (float)r[j];
        outv[j] = (_Float16)fmaxf(v, 0.f);
    }
    *(f16x8*)(h + (size_t)n * HP + cof) = outv;
}

// ---------------- pooling ----------------

__global__ void gstarts_kernel(const int* __restrict__ batch, int* __restrict__ gstart, int n) {
    int i = blockIdx.x * blockDim.x + threadIdx.x;
    if (i >= n) return;
    int b = batch[i];
    int prev = (i == 0) ? -1 : batch[i - 1];
    for (int g = prev + 1; g <= b; ++g) gstart[g] = i;
    if (i == n - 1) {
        for (int g = b + 1; g <= NG; ++g) gstart[g] = n;
    }
}

__global__ __launch_bounds__(256) void pool_kernel(const __half2* __restrict__ h2,
                                                   const int* __restrict__ gstart,
                                                   float* __restrict__ pooled) {
    __shared__ float red[4][F2][2];
    const int g    = blockIdx.x;
    const int w    = threadIdx.x >> 6;
    const int lane = threadIdx.x & 63;
    const int s = gstart[g], e = gstart[g + 1];

    float ax0 = 0.f, ay0 = 0.f, ax1 = 0.f, ay1 = 0.f;
    if (lane < F2) {
        int n = s + w;
        for (; n + 4 < e; n += 8) {
            __half2 v0 = h2[(size_t)n * HP2 + lane];
            __half2 v1 = h2[(size_t)(n + 4) * HP2 + lane];
            ax0 += __low2float(v0); ay0 += __high2float(v0);
            ax1 += __low2float(v1); ay1 += __high2float(v1);
        }
        if (n < e) {
            __half2 v0 = h2[(size_t)n * HP2 + lane];
            ax0 += __low2float(v0); ay0 += __high2float(v0);
        }
        red[w][lane][0] = ax0 + ax1;
        red[w][lane][1] = ay0 + ay1;
    }
    __syncthreads();
    if (threadIdx.x < F2) {
        const int fp = threadIdx.x;
        float sx = red[0][fp][0] + red[1][fp][0] + red[2][fp][0] + red[3][fp][0];
        float sy = red[0][fp][1] + red[1][fp][1] + red[2][fp][1] + red[3][fp][1];
        float2* pp = (float2*)(pooled + (size_t)g * MD);
        pp[fp] = make_float2(sx, sy);
    }
}

__global__ void final_kernel(const float* __restrict__ pooled, const float* __restrict__ Wlin,
                             const float* __restrict__ blin, float* __restrict__ out) {
    int idx = blockIdx.x * blockDim.x + threadIdx.x;
    if (idx >= NG * OD) return;
    int g = idx / OD, o = idx - (idx / OD) * OD;
    float acc = blin[o];
    for (int f = 0; f < MD; ++f)
        acc = fmaf(pooled[g * MD + f], Wlin[f * OD + o], acc);
    out[idx] = acc;
}

// ---------------- launch ----------------

extern "C" void kernel_launch(void* const* d_in, const int* in_sizes, int n_in,
                              void* d_out, int out_size, void* d_ws, size_t ws_size,
                              hipStream_t stream) {
    const float* x     = (const float*)d_in[0];
    const int*   edge  = (const int*)d_in[1];
    const int*   batch = (const int*)d_in[2];
    const float* W1l = (const float*)d_in[3];
    const float* W1r = (const float*)d_in[4];
    const float* b1  = (const float*)d_in[5];
    const float* W2l = (const float*)d_in[6];
    const float* W2r = (const float*)d_in[7];
    const float* b2  = (const float*)d_in[8];
    const float* W3l = (const float*)d_in[9];
    const float* W3r = (const float*)d_in[10];
    const float* b3  = (const float*)d_in[11];
    const float* Wlin = (const float*)d_in[12];
    const float* blin = (const float*)d_in[13];
    float* out = (float*)d_out;

    const int N = in_sizes[0] / CF;     // 50000
    const int E = in_sizes[1] / 2;      // 800000

    char* ws = (char*)d_ws;
    auto alloc = [&](size_t bytes) -> void* {
        void* p = (void*)ws;
        ws += (bytes + 255) & ~(size_t)255;
        return p;
    };
    int*       sbcur   = (int*)alloc((size_t)NSB * 4);
    unsigned*  sbrec   = (unsigned*)alloc((size_t)NSB * SBCAP * 4);
    int*       csr     = (int*)alloc((size_t)NSB * SBCAP * 4);
    int2*      off2    = (int2*)alloc((size_t)N * 8);
    int*       gstart  = (int*)alloc((size_t)(NG + 1) * 4);
    _Float16*  Wct     = (_Float16*)alloc((size_t)176 * K1P * 2);
    _Float16*  xh      = (_Float16*)alloc((size_t)N * K1P * 2);
    _Float16*  yl      = (_Float16*)alloc((size_t)N * MD * 2);
    _Float16*  yr      = (_Float16*)alloc((size_t)N * MD * 2);
    _Float16*  h       = (_Float16*)alloc((size_t)N * HP * 2);
    float*     pooled  = (float*)alloc((size_t)NG * MD * 4);

    hipMemsetAsync(sbcur, 0, (size_t)NSB * 4, stream);
    bin_kernel<<<(E + TILE - 1) / TILE, 256, 0, stream>>>(edge, E, sbcur, sbrec);
    csr256_kernel<<<NSB, 256, 0, stream>>>(sbrec, sbcur, csr, off2, N);

    convx_kernel<<<(N * K1P + 255) / 256, 256, 0, stream>>>(x, xh, N);

    const int gemm_blocks = (N + 63) / 64;
    const int agg_blocks  = (N * NCH + 255) / 256;

    // layer 1 (K=108, KPAD=128)
    build_wct_kernel<<<(176 * K1P + 255) / 256, 256, 0, stream>>>(W1l, W1r, Wct, CF, K1P);
    gemm_mfma_kernel<K1P><<<gemm_blocks, 256, 0, stream>>>(xh, Wct, b1, yl, yr, N);
    agg_kernel<<<agg_blocks, 256, 0, stream>>>(yl, yr, off2, csr, h, N);

    // layer 2 (K=88, KPAD=96)
    build_wct_kernel<<<(176 * HP + 255) / 256, 256, 0, stream>>>(W2l, W2r, Wct, MD, HP);
    gemm_mfma_kernel<HP><<<gemm_blocks, 256, 0, stream>>>(h, Wct, b2, yl, yr, N);
    agg_kernel<<<agg_blocks, 256, 0, stream>>>(yl, yr, off2, csr, h, N);

    // layer 3 (K=88, KPAD=96)
    build_wct_kernel<<<(176 * HP + 255) / 256, 256, 0, stream>>>(W3l, W3r, Wct, MD, HP);
    gemm_mfma_kernel<HP><<<gemm_blocks, 256, 0, stream>>>(h, Wct, b3, yl, yr, N);
    agg_kernel<<<agg_blocks, 256, 0, stream>>>(yl, yr, off2, csr, h, N);

    // pool + classifier
    gstarts_kernel<<<(N + 255) / 256, 256, 0, stream>>>(batch, gstart, N);
    pool_kernel<<<NG, 256, 0, stream>>>((const __half2*)h, gstart, pooled);
    final_kernel<<<(NG * OD + 255) / 256, 256, 0, stream>>>(pooled, Wlin, blin, out);
}

// Round 11
// 215.460 us; speedup vs baseline: 7.7442x; 1.0368x over previous
//
#include <hip/hip_runtime.h>
#include <hip/hip_fp16.h>

#define NN 50000
#define NG 256
#define CF 108
#define MD 88
#define OD 100
#define F2 44    // half2 per 88-feat row
#define HP 96    // h row stride in halfs (88 + 8 zero pad, MFMA K=96)
#define HP2 48   // h row stride in half2
#define YLS 96   // yl row stride in halfs (192B: rows span exactly 2x128B lines)
#define K1P 128  // layer-1 K padded (108 -> 128)
#define NSB 196      // super-buckets of 256 nodes
#define SBCAP 5120   // records per super-bucket (avg 4096)
#define TILE 2048    // edges per bin_kernel block
#define NCH 12       // 16B chunks per node in agg (11 real + 1 pad)

typedef _Float16 f16x8 __attribute__((ext_vector_type(8)));
typedef float f32x4 __attribute__((ext_vector_type(4)));

// ---------------- phase A: LDS-staged binning (dense chunk writes) ----------------
// record = (src<<8) | (dst & 255), bin = dst>>8

__global__ __launch_bounds__(256) void bin_kernel(const int* __restrict__ edge, int E,
                                                  int* __restrict__ sbcur,
                                                  unsigned* __restrict__ sbrec) {
    __shared__ int bcnt[NSB], boff[NSB], bfill[NSB], gbase[NSB];
    __shared__ int sc[256];
    __shared__ unsigned stag[TILE];
    __shared__ unsigned char stagbin[TILE];
    const int tid = threadIdx.x;
    const int t0  = blockIdx.x * TILE;
    const int tcnt = min(TILE, E - t0);

    for (int i = tid; i < NSB; i += 256) bcnt[i] = 0;
    __syncthreads();

    unsigned recs[TILE / 256];
    int      bins[TILE / 256];
    #pragma unroll
    for (int j = 0; j < TILE / 256; ++j) {
        const int e = t0 + j * 256 + tid;
        bins[j] = -1;
        if (e < E) {
            const int dst = edge[E + e], src = edge[e];
            bins[j] = dst >> 8;
            recs[j] = ((unsigned)src << 8) | (unsigned)(dst & 255);
            atomicAdd(&bcnt[bins[j]], 1);
        }
    }
    __syncthreads();

    sc[tid] = (tid < NSB) ? bcnt[tid] : 0;
    __syncthreads();
    for (int d = 1; d < 256; d <<= 1) {
        int v = (tid >= d) ? sc[tid - d] : 0;
        __syncthreads();
        sc[tid] += v;
        __syncthreads();
    }
    if (tid < NSB) {
        boff[tid]  = sc[tid] - bcnt[tid];
        bfill[tid] = sc[tid] - bcnt[tid];
        if (bcnt[tid] > 0) gbase[tid] = atomicAdd(&sbcur[tid], bcnt[tid]);
    }
    __syncthreads();

    #pragma unroll
    for (int j = 0; j < TILE / 256; ++j) {
        if (bins[j] >= 0) {
            int pos = atomicAdd(&bfill[bins[j]], 1);
            stag[pos]    = recs[j];
            stagbin[pos] = (unsigned char)bins[j];
        }
    }
    __syncthreads();

    for (int i = tid; i < tcnt; i += 256) {
        const int b   = stagbin[i];
        const int rel = i - boff[b];
        const int gp  = gbase[b] + rel;
        if (gp < SBCAP) sbrec[(size_t)b * SBCAP + gp] = stag[i];
    }
}

// ---------------- phase B: per-super-bucket CSR ----------------

__global__ __launch_bounds__(256) void csr256_kernel(const unsigned* __restrict__ sbrec,
                                                     const int* __restrict__ sbcur,
                                                     int* __restrict__ csr,
                                                     int2* __restrict__ off2, int N) {
    __shared__ int hist[256], base[256], offc[256], sc[256];
    const int b = blockIdx.x, tid = threadIdx.x;
    const int cnt = min(sbcur[b], SBCAP);
    const unsigned* rec = sbrec + (size_t)b * SBCAP;

    hist[tid] = 0;
    __syncthreads();
    for (int r = tid; r < cnt; r += 256) atomicAdd(&hist[rec[r] & 255u], 1);
    __syncthreads();

    sc[tid] = hist[tid];
    __syncthreads();
    for (int d = 1; d < 256; d <<= 1) {
        int v = (tid >= d) ? sc[tid - d] : 0;
        __syncthreads();
        sc[tid] += v;
        __syncthreads();
    }
    base[tid] = sc[tid] - hist[tid];
    offc[tid] = base[tid];
    __syncthreads();

    for (int r = tid; r < cnt; r += 256) {
        const unsigned u = rec[r];
        const int dl = (int)(u & 255u);
        const int pos = atomicAdd(&offc[dl], 1);
        csr[(size_t)b * SBCAP + pos] = (int)(u >> 8);
    }
    __syncthreads();

    const int n = b * 256 + tid;
    if (n < N) off2[n] = make_int2(b * SBCAP + base[tid], hist[tid]);
}

// ---------------- x -> f16 padded [N][128] ----------------

__global__ void convx_kernel(const float* __restrict__ x, _Float16* __restrict__ xh, int N) {
    int i = blockIdx.x * blockDim.x + threadIdx.x;
    if (i >= N * K1P) return;
    int n = i >> 7, k = i & (K1P - 1);
    xh[i] = (k < CF) ? (_Float16)x[n * CF + k] : (_Float16)0.f;
}

// ---------------- all transposed combined weights in one launch ----------------
// Wct1[176][128] for layer 1; Wct23[2][176][96] for layers 2,3

__global__ void build_wct_all(const float* __restrict__ W1l, const float* __restrict__ W1r,
                              const float* __restrict__ W2l, const float* __restrict__ W2r,
                              const float* __restrict__ W3l, const float* __restrict__ W3r,
                              _Float16* __restrict__ Wct1, _Float16* __restrict__ Wct23) {
    const int n1 = 176 * K1P;
    const int n2 = 176 * HP;
    int idx = blockIdx.x * blockDim.x + threadIdx.x;
    if (idx < n1) {
        int c = idx / K1P, k = idx - c * K1P;
        float v = (k < CF) ? ((c < MD) ? W1l[k * MD + c] : W1r[k * MD + (c - MD)]) : 0.f;
        Wct1[idx] = (_Float16)v;
    } else if (idx < n1 + 2 * n2) {
        int j = idx - n1;
        const float* Wl = (j < n2) ? W2l : W3l;
        const float* Wr = (j < n2) ? W2r : W3r;
        int jj = (j < n2) ? j : j - n2;
        int c = jj / HP, k = jj - c * HP;
        float v = (k < MD) ? ((c < MD) ? Wl[k * MD + c] : Wr[k * MD + (c - MD)]) : 0.f;
        Wct23[j] = (_Float16)v;
    }
}

// ---------------- MFMA GEMM: yl[N][96-stride] / yr[N][88] (f16) = A[N,KPAD] @ Wct^T ------

template <int KPAD>
__global__ __launch_bounds__(256) void gemm_mfma_kernel(const _Float16* __restrict__ Ah,
                                                        const _Float16* __restrict__ Wct,
                                                        const float* __restrict__ bias,
                                                        _Float16* __restrict__ yl,
                                                        _Float16* __restrict__ yr, int N) {
    const int wave = threadIdx.x >> 6;
    const int lane = threadIdx.x & 63;
    const int r16  = lane & 15;
    const int kg   = lane >> 4;
    const int rbase = blockIdx.x * 64 + wave * 16;

    const int arow = min(rbase + r16, N - 1);
    const _Float16* ap = Ah + (size_t)arow * KPAD + kg * 8;

    f32x4 acc[11];
    #pragma unroll
    for (int t = 0; t < 11; ++t) acc[t] = (f32x4){0.f, 0.f, 0.f, 0.f};

    #pragma unroll
    for (int ks = 0; ks < KPAD / 32; ++ks) {
        f16x8 af = *(const f16x8*)(ap + ks * 32);
        #pragma unroll
        for (int t = 0; t < 11; ++t) {
            const _Float16* bp = Wct + (size_t)(t * 16 + r16) * KPAD + ks * 32 + kg * 8;
            f16x8 bf = *(const f16x8*)bp;
            acc[t] = __builtin_amdgcn_mfma_f32_16x16x32_f16(af, bf, acc[t], 0, 0, 0);
        }
    }

    const int orow0 = rbase + kg * 4;
    #pragma unroll
    for (int t = 0; t < 11; ++t) {
        const int c = t * 16 + r16;
        const bool isr = (c >= MD);
        const float bv = isr ? bias[c - MD] : 0.f;
        _Float16* dst = isr ? (yr + (c - MD)) : (yl + c);
        const int st = isr ? MD : YLS;
        #pragma unroll
        for (int r = 0; r < 4; ++r) {
            const int row = orow0 + r;
            if (row < N) dst[(size_t)row * st] = (_Float16)(acc[t][r] + bv);
        }
    }
}

// ---------------- fused aggregate: 16B gathers, thread per (node, chunk) ----------------
// idx = n*12 + c; c in [0,11): 16B chunk of the 176B row; c==11 writes the 16B pad.

__global__ void agg_kernel(const _Float16* __restrict__ yl, const _Float16* __restrict__ yr,
                           const int2* __restrict__ off2, const int* __restrict__ csr,
                           _Float16* __restrict__ h, int N) {
    int idx = blockIdx.x * blockDim.x + threadIdx.x;
    if (idx >= N * NCH) return;
    int n = idx / NCH;
    int c = idx - n * NCH;
    if (c >= 11) {
        *(f16x8*)(h + (size_t)n * HP + 88) = (f16x8)(_Float16)0.f;
        return;
    }
    const int2 o = off2[n];
    const int s = o.x, e = o.x + o.y;
    float a0[8] = {0,0,0,0,0,0,0,0}, a1[8] = {0,0,0,0,0,0,0,0};
    float a2[8] = {0,0,0,0,0,0,0,0}, a3[8] = {0,0,0,0,0,0,0,0};
    const size_t cof = (size_t)c * 8;
    int i = s;
    for (; i + 3 < e; i += 4) {
        f16x8 v0 = *(const f16x8*)(yl + (size_t)csr[i]     * YLS + cof);
        f16x8 v1 = *(const f16x8*)(yl + (size_t)csr[i + 1] * YLS + cof);
        f16x8 v2 = *(const f16x8*)(yl + (size_t)csr[i + 2] * YLS + cof);
        f16x8 v3 = *(const f16x8*)(yl + (size_t)csr[i + 3] * YLS + cof);
        #pragma unroll
        for (int j = 0; j < 8; ++j) {
            a0[j] += (float)v0[j]; a1[j] += (float)v1[j];
            a2[j] += (float)v2[j]; a3[j] += (float)v3[j];
        }
    }
    for (; i < e; ++i) {
        f16x8 v0 = *(const f16x8*)(yl + (size_t)csr[i] * YLS + cof);
        #pragma unroll
        for (int j = 0; j < 8; ++j) a0[j] += (float)v0[j];
    }
    const float inv = 1.0f / (float)max(o.y, 1);
    const f16x8 r = *(const f16x8*)(yr + (size_t)n * MD + cof);
    f16x8 outv;
    #pragma unroll
    for (int j = 0; j < 8; ++j) {
        float v = (a0[j] + a1[j] + a2[j] + a3[j]) * inv + (float)r[j];
        outv[j] = (_Float16)fmaxf(v, 0.f);
    }
    *(f16x8*)(h + (size_t)n * HP + cof) = outv;
}

// ---------------- pooling ----------------

__global__ void gstarts_kernel(const int* __restrict__ batch, int* __restrict__ gstart, int n) {
    int i = blockIdx.x * blockDim.x + threadIdx.x;
    if (i >= n) return;
    int b = batch[i];
    int prev = (i == 0) ? -1 : batch[i - 1];
    for (int g = prev + 1; g <= b; ++g) gstart[g] = i;
    if (i == n - 1) {
        for (int g = b + 1; g <= NG; ++g) gstart[g] = n;
    }
}

__global__ __launch_bounds__(256) void pool_kernel(const __half2* __restrict__ h2,
                                                   const int* __restrict__ gstart,
                                                   float* __restrict__ pooled) {
    __shared__ float red[4][F2][2];
    const int g    = blockIdx.x;
    const int w    = threadIdx.x >> 6;
    const int lane = threadIdx.x & 63;
    const int s = gstart[g], e = gstart[g + 1];

    float ax0 = 0.f, ay0 = 0.f, ax1 = 0.f, ay1 = 0.f;
    if (lane < F2) {
        int n = s + w;
        for (; n + 4 < e; n += 8) {
            __half2 v0 = h2[(size_t)n * HP2 + lane];
            __half2 v1 = h2[(size_t)(n + 4) * HP2 + lane];
            ax0 += __low2float(v0); ay0 += __high2float(v0);
            ax1 += __low2float(v1); ay1 += __high2float(v1);
        }
        if (n < e) {
            __half2 v0 = h2[(size_t)n * HP2 + lane];
            ax0 += __low2float(v0); ay0 += __high2float(v0);
        }
        red[w][lane][0] = ax0 + ax1;
        red[w][lane][1] = ay0 + ay1;
    }
    __syncthreads();
    if (threadIdx.x < F2) {
        const int fp = threadIdx.x;
        float sx = red[0][fp][0] + red[1][fp][0] + red[2][fp][0] + red[3][fp][0];
        float sy = red[0][fp][1] + red[1][fp][1] + red[2][fp][1] + red[3][fp][1];
        float2* pp = (float2*)(pooled + (size_t)g * MD);
        pp[fp] = make_float2(sx, sy);
    }
}

__global__ void final_kernel(const float* __restrict__ pooled, const float* __restrict__ Wlin,
                             const float* __restrict__ blin, float* __restrict__ out) {
    int idx = blockIdx.x * blockDim.x + threadIdx.x;
    if (idx >= NG * OD) return;
    int g = idx / OD, o = idx - (idx / OD) * OD;
    float acc = blin[o];
    for (int f = 0; f < MD; ++f)
        acc = fmaf(pooled[g * MD + f], Wlin[f * OD + o], acc);
    out[idx] = acc;
}

// ---------------- launch ----------------

extern "C" void kernel_launch(void* const* d_in, const int* in_sizes, int n_in,
                              void* d_out, int out_size, void* d_ws, size_t ws_size,
                              hipStream_t stream) {
    const float* x     = (const float*)d_in[0];
    const int*   edge  = (const int*)d_in[1];
    const int*   batch = (const int*)d_in[2];
    const float* W1l = (const float*)d_in[3];
    const float* W1r = (const float*)d_in[4];
    const float* b1  = (const float*)d_in[5];
    const float* W2l = (const float*)d_in[6];
    const float* W2r = (const float*)d_in[7];
    const float* b2  = (const float*)d_in[8];
    const float* W3l = (const float*)d_in[9];
    const float* W3r = (const float*)d_in[10];
    const float* b3  = (const float*)d_in[11];
    const float* Wlin = (const float*)d_in[12];
    const float* blin = (const float*)d_in[13];
    float* out = (float*)d_out;

    const int N = in_sizes[0] / CF;     // 50000
    const int E = in_sizes[1] / 2;      // 800000

    char* ws = (char*)d_ws;
    auto alloc = [&](size_t bytes) -> void* {
        void* p = (void*)ws;
        ws += (bytes + 255) & ~(size_t)255;
        return p;
    };
    int*       sbcur   = (int*)alloc((size_t)NSB * 4);
    unsigned*  sbrec   = (unsigned*)alloc((size_t)NSB * SBCAP * 4);
    int*       csr     = (int*)alloc((size_t)NSB * SBCAP * 4);
    int2*      off2    = (int2*)alloc((size_t)N * 8);
    int*       gstart  = (int*)alloc((size_t)(NG + 1) * 4);
    _Float16*  Wct1    = (_Float16*)alloc((size_t)176 * K1P * 2);
    _Float16*  Wct23   = (_Float16*)alloc((size_t)2 * 176 * HP * 2);
    _Float16*  xh      = (_Float16*)alloc((size_t)N * K1P * 2);
    _Float16*  yl      = (_Float16*)alloc((size_t)N * YLS * 2);
    _Float16*  yr      = (_Float16*)alloc((size_t)N * MD * 2);
    _Float16*  h       = (_Float16*)alloc((size_t)N * HP * 2);
    float*     pooled  = (float*)alloc((size_t)NG * MD * 4);

    hipMemsetAsync(sbcur, 0, (size_t)NSB * 4, stream);
    bin_kernel<<<(E + TILE - 1) / TILE, 256, 0, stream>>>(edge, E, sbcur, sbrec);
    csr256_kernel<<<NSB, 256, 0, stream>>>(sbrec, sbcur, csr, off2, N);

    convx_kernel<<<(N * K1P + 255) / 256, 256, 0, stream>>>(x, xh, N);
    build_wct_all<<<(176 * K1P + 2 * 176 * HP + 255) / 256, 256, 0, stream>>>(
        W1l, W1r, W2l, W2r, W3l, W3r, Wct1, Wct23);
    gstarts_kernel<<<(N + 255) / 256, 256, 0, stream>>>(batch, gstart, N);

    const int gemm_blocks = (N + 63) / 64;
    const int agg_blocks  = (N * NCH + 255) / 256;

    // layer 1 (K=108, KPAD=128)
    gemm_mfma_kernel<K1P><<<gemm_blocks, 256, 0, stream>>>(xh, Wct1, b1, yl, yr, N);
    agg_kernel<<<agg_blocks, 256, 0, stream>>>(yl, yr, off2, csr, h, N);

    // layer 2 (K=88, KPAD=96)
    gemm_mfma_kernel<HP><<<gemm_blocks, 256, 0, stream>>>(h, Wct23, b2, yl, yr, N);
    agg_kernel<<<agg_blocks, 256, 0, stream>>>(yl, yr, off2, csr, h, N);

    // layer 3 (K=88, KPAD=96)
    gemm_mfma_kernel<HP><<<gemm_blocks, 256, 0, stream>>>(h, Wct23 + (size_t)176 * HP, b3, yl, yr, N);
    agg_kernel<<<agg_blocks, 256, 0, stream>>>(yl, yr, off2, csr, h, N);

    // pool + classifier
    pool_kernel<<<NG, 256, 0, stream>>>((const __half2*)h, gstart, pooled);
    final_kernel<<<(NG * OD + 255) / 256, 256, 0, stream>>>(pooled, Wlin, blin, out);
}

// Round 12
// 209.358 us; speedup vs baseline: 7.9699x; 1.0291x over previous
//
#include <hip/hip_runtime.h>
#include <hip/hip_fp16.h>

#define NN 50000
#define NG 256
#define CF 108
#define MD 88
#define OD 100
#define F2 44    // half2 per 88-feat row
#define HP 96    // h row stride in halfs (88 + 8 zero pad, MFMA K=96)
#define HP2 48   // h row stride in half2
#define YLS 96   // yl row stride in halfs (192B: rows span exactly 2x128B lines)
#define K1P 128  // layer-1 K padded (108 -> 128)
#define NSB 196      // super-buckets of 256 nodes
#define SBCAP 5120   // records per super-bucket (avg 4096)
#define TILE 2048    // edges per bin_kernel block
#define NCH 12       // 16B chunks per node in agg (11 real + 1 pad)

typedef _Float16 f16x8 __attribute__((ext_vector_type(8)));
typedef float f32x4 __attribute__((ext_vector_type(4)));

// ---------------- phase A: LDS-staged binning (dense chunk writes) ----------------

__global__ __launch_bounds__(256) void bin_kernel(const int* __restrict__ edge, int E,
                                                  int* __restrict__ sbcur,
                                                  unsigned* __restrict__ sbrec) {
    __shared__ int bcnt[NSB], boff[NSB], bfill[NSB], gbase[NSB];
    __shared__ int sc[256];
    __shared__ unsigned stag[TILE];
    __shared__ unsigned char stagbin[TILE];
    const int tid = threadIdx.x;
    const int t0  = blockIdx.x * TILE;
    const int tcnt = min(TILE, E - t0);

    for (int i = tid; i < NSB; i += 256) bcnt[i] = 0;
    __syncthreads();

    unsigned recs[TILE / 256];
    int      bins[TILE / 256];
    #pragma unroll
    for (int j = 0; j < TILE / 256; ++j) {
        const int e = t0 + j * 256 + tid;
        bins[j] = -1;
        if (e < E) {
            const int dst = edge[E + e], src = edge[e];
            bins[j] = dst >> 8;
            recs[j] = ((unsigned)src << 8) | (unsigned)(dst & 255);
            atomicAdd(&bcnt[bins[j]], 1);
        }
    }
    __syncthreads();

    sc[tid] = (tid < NSB) ? bcnt[tid] : 0;
    __syncthreads();
    for (int d = 1; d < 256; d <<= 1) {
        int v = (tid >= d) ? sc[tid - d] : 0;
        __syncthreads();
        sc[tid] += v;
        __syncthreads();
    }
    if (tid < NSB) {
        boff[tid]  = sc[tid] - bcnt[tid];
        bfill[tid] = sc[tid] - bcnt[tid];
        if (bcnt[tid] > 0) gbase[tid] = atomicAdd(&sbcur[tid], bcnt[tid]);
    }
    __syncthreads();

    #pragma unroll
    for (int j = 0; j < TILE / 256; ++j) {
        if (bins[j] >= 0) {
            int pos = atomicAdd(&bfill[bins[j]], 1);
            stag[pos]    = recs[j];
            stagbin[pos] = (unsigned char)bins[j];
        }
    }
    __syncthreads();

    for (int i = tid; i < tcnt; i += 256) {
        const int b   = stagbin[i];
        const int rel = i - boff[b];
        const int gp  = gbase[b] + rel;
        if (gp < SBCAP) sbrec[(size_t)b * SBCAP + gp] = stag[i];
    }
}

// ---------------- phase B: per-super-bucket CSR ----------------

__global__ __launch_bounds__(256) void csr256_kernel(const unsigned* __restrict__ sbrec,
                                                     const int* __restrict__ sbcur,
                                                     int* __restrict__ csr,
                                                     int2* __restrict__ off2, int N) {
    __shared__ int hist[256], base[256], offc[256], sc[256];
    const int b = blockIdx.x, tid = threadIdx.x;
    const int cnt = min(sbcur[b], SBCAP);
    const unsigned* rec = sbrec + (size_t)b * SBCAP;

    hist[tid] = 0;
    __syncthreads();
    for (int r = tid; r < cnt; r += 256) atomicAdd(&hist[rec[r] & 255u], 1);
    __syncthreads();

    sc[tid] = hist[tid];
    __syncthreads();
    for (int d = 1; d < 256; d <<= 1) {
        int v = (tid >= d) ? sc[tid - d] : 0;
        __syncthreads();
        sc[tid] += v;
        __syncthreads();
    }
    base[tid] = sc[tid] - hist[tid];
    offc[tid] = base[tid];
    __syncthreads();

    for (int r = tid; r < cnt; r += 256) {
        const unsigned u = rec[r];
        const int dl = (int)(u & 255u);
        const int pos = atomicAdd(&offc[dl], 1);
        csr[(size_t)b * SBCAP + pos] = (int)(u >> 8);
    }
    __syncthreads();

    const int n = b * 256 + tid;
    if (n < N) off2[n] = make_int2(b * SBCAP + base[tid], hist[tid]);
}

// ---------------- x -> f16 padded [N][128] ----------------

__global__ void convx_kernel(const float* __restrict__ x, _Float16* __restrict__ xh, int N) {
    int i = blockIdx.x * blockDim.x + threadIdx.x;
    if (i >= N * K1P) return;
    int n = i >> 7, k = i & (K1P - 1);
    xh[i] = (k < CF) ? (_Float16)x[n * CF + k] : (_Float16)0.f;
}

// ---------------- all transposed combined weights in one launch ----------------

__global__ void build_wct_all(const float* __restrict__ W1l, const float* __restrict__ W1r,
                              const float* __restrict__ W2l, const float* __restrict__ W2r,
                              const float* __restrict__ W3l, const float* __restrict__ W3r,
                              _Float16* __restrict__ Wct1, _Float16* __restrict__ Wct23) {
    const int n1 = 176 * K1P;
    const int n2 = 176 * HP;
    int idx = blockIdx.x * blockDim.x + threadIdx.x;
    if (idx < n1) {
        int c = idx / K1P, k = idx - c * K1P;
        float v = (k < CF) ? ((c < MD) ? W1l[k * MD + c] : W1r[k * MD + (c - MD)]) : 0.f;
        Wct1[idx] = (_Float16)v;
    } else if (idx < n1 + 2 * n2) {
        int j = idx - n1;
        const float* Wl = (j < n2) ? W2l : W3l;
        const float* Wr = (j < n2) ? W2r : W3r;
        int jj = (j < n2) ? j : j - n2;
        int c = jj / HP, k = jj - c * HP;
        float v = (k < MD) ? ((c < MD) ? Wl[k * MD + c] : Wr[k * MD + (c - MD)]) : 0.f;
        Wct23[j] = (_Float16)v;
    }
}

// ---------------- MFMA GEMM: 128 rows/block, 2 row-tiles per wave (B reuse) ----------------

template <int KPAD>
__global__ __launch_bounds__(256) void gemm_mfma_kernel(const _Float16* __restrict__ Ah,
                                                        const _Float16* __restrict__ Wct,
                                                        const float* __restrict__ bias,
                                                        _Float16* __restrict__ yl,
                                                        _Float16* __restrict__ yr, int N) {
    const int wave = threadIdx.x >> 6;
    const int lane = threadIdx.x & 63;
    const int r16  = lane & 15;
    const int kg   = lane >> 4;
    const int rbase = blockIdx.x * 128 + wave * 16;   // row-tile 0; tile 1 at +64

    const int arow0 = min(rbase + r16, N - 1);
    const int arow1 = min(rbase + 64 + r16, N - 1);
    const _Float16* ap0 = Ah + (size_t)arow0 * KPAD + kg * 8;
    const _Float16* ap1 = Ah + (size_t)arow1 * KPAD + kg * 8;

    f32x4 acc[2][11];
    #pragma unroll
    for (int q = 0; q < 2; ++q)
        #pragma unroll
        for (int t = 0; t < 11; ++t) acc[q][t] = (f32x4){0.f, 0.f, 0.f, 0.f};

    #pragma unroll
    for (int ks = 0; ks < KPAD / 32; ++ks) {
        f16x8 af0 = *(const f16x8*)(ap0 + ks * 32);
        f16x8 af1 = *(const f16x8*)(ap1 + ks * 32);
        #pragma unroll
        for (int t = 0; t < 11; ++t) {
            const _Float16* bp = Wct + (size_t)(t * 16 + r16) * KPAD + ks * 32 + kg * 8;
            f16x8 bf = *(const f16x8*)bp;
            acc[0][t] = __builtin_amdgcn_mfma_f32_16x16x32_f16(af0, bf, acc[0][t], 0, 0, 0);
            acc[1][t] = __builtin_amdgcn_mfma_f32_16x16x32_f16(af1, bf, acc[1][t], 0, 0, 0);
        }
    }

    #pragma unroll
    for (int q = 0; q < 2; ++q) {
        const int orow0 = rbase + q * 64 + kg * 4;
        #pragma unroll
        for (int t = 0; t < 11; ++t) {
            const int c = t * 16 + r16;
            const bool isr = (c >= MD);
            const float bv = isr ? bias[c - MD] : 0.f;
            _Float16* dst = isr ? (yr + (c - MD)) : (yl + c);
            const int st = isr ? MD : YLS;
            #pragma unroll
            for (int r = 0; r < 4; ++r) {
                const int row = orow0 + r;
                if (row < N) dst[(size_t)row * st] = (_Float16)(acc[q][t][r] + bv);
            }
        }
    }
}

// ---------------- fused aggregate: 16B gathers, 8-deep unroll ----------------

__global__ void agg_kernel(const _Float16* __restrict__ yl, const _Float16* __restrict__ yr,
                           const int2* __restrict__ off2, const int* __restrict__ csr,
                           _Float16* __restrict__ h, int N) {
    int idx = blockIdx.x * blockDim.x + threadIdx.x;
    if (idx >= N * NCH) return;
    int n = idx / NCH;
    int c = idx - n * NCH;
    if (c >= 11) {
        *(f16x8*)(h + (size_t)n * HP + 88) = (f16x8)(_Float16)0.f;
        return;
    }
    const int2 o = off2[n];
    const int s = o.x, e = o.x + o.y;
    float a0[8] = {0,0,0,0,0,0,0,0}, a1[8] = {0,0,0,0,0,0,0,0};
    float a2[8] = {0,0,0,0,0,0,0,0}, a3[8] = {0,0,0,0,0,0,0,0};
    const size_t cof = (size_t)c * 8;
    int i = s;
    for (; i + 7 < e; i += 8) {
        f16x8 v0 = *(const f16x8*)(yl + (size_t)csr[i]     * YLS + cof);
        f16x8 v1 = *(const f16x8*)(yl + (size_t)csr[i + 1] * YLS + cof);
        f16x8 v2 = *(const f16x8*)(yl + (size_t)csr[i + 2] * YLS + cof);
        f16x8 v3 = *(const f16x8*)(yl + (size_t)csr[i + 3] * YLS + cof);
        f16x8 v4 = *(const f16x8*)(yl + (size_t)csr[i + 4] * YLS + cof);
        f16x8 v5 = *(const f16x8*)(yl + (size_t)csr[i + 5] * YLS + cof);
        f16x8 v6 = *(const f16x8*)(yl + (size_t)csr[i + 6] * YLS + cof);
        f16x8 v7 = *(const f16x8*)(yl + (size_t)csr[i + 7] * YLS + cof);
        #pragma unroll
        for (int j = 0; j < 8; ++j) {
            a0[j] += (float)v0[j] + (float)v1[j];
            a1[j] += (float)v2[j] + (float)v3[j];
            a2[j] += (float)v4[j] + (float)v5[j];
            a3[j] += (float)v6[j] + (float)v7[j];
        }
    }
    for (; i + 1 < e; i += 2) {
        f16x8 v0 = *(const f16x8*)(yl + (size_t)csr[i]     * YLS + cof);
        f16x8 v1 = *(const f16x8*)(yl + (size_t)csr[i + 1] * YLS + cof);
        #pragma unroll
        for (int j = 0; j < 8; ++j) {
            a0[j] += (float)v0[j];
            a1[j] += (float)v1[j];
        }
    }
    if (i < e) {
        f16x8 v0 = *(const f16x8*)(yl + (size_t)csr[i] * YLS + cof);
        #pragma unroll
        for (int j = 0; j < 8; ++j) a0[j] += (float)v0[j];
    }
    const float inv = 1.0f / (float)max(o.y, 1);
    const f16x8 r = *(const f16x8*)(yr + (size_t)n * MD + cof);
    f16x8 outv;
    #pragma unroll
    for (int j = 0; j < 8; ++j) {
        float v = (a0[j] + a1[j] + a2[j] + a3[j]) * inv + (float)r[j];
        outv[j] = (_Float16)fmaxf(v, 0.f);
    }
    *(f16x8*)(h + (size_t)n * HP + cof) = outv;
}

// ---------------- fused pool + classifier: block per graph ----------------

__global__ __launch_bounds__(256) void pool_final_kernel(const __half2* __restrict__ h2,
                                                         const int* __restrict__ batch,
                                                         const float* __restrict__ Wlin,
                                                         const float* __restrict__ blin,
                                                         float* __restrict__ out, int N) {
    __shared__ float red[4][F2][2];
    __shared__ float pooled[MD];
    __shared__ int range[2];
    const int g    = blockIdx.x;
    const int tid  = threadIdx.x;
    const int w    = tid >> 6;
    const int lane = tid & 63;

    if (tid < 2) {
        const int tgt = g + tid;   // lower_bound(batch, tgt)
        int lo = 0, hi = N;
        while (lo < hi) {
            int mid = (lo + hi) >> 1;
            if (batch[mid] < tgt) lo = mid + 1; else hi = mid;
        }
        range[tid] = lo;
    }
    __syncthreads();
    const int s = range[0], e = range[1];

    float ax0 = 0.f, ay0 = 0.f, ax1 = 0.f, ay1 = 0.f;
    if (lane < F2) {
        int n = s + w;
        for (; n + 4 < e; n += 8) {
            __half2 v0 = h2[(size_t)n * HP2 + lane];
            __half2 v1 = h2[(size_t)(n + 4) * HP2 + lane];
            ax0 += __low2float(v0); ay0 += __high2float(v0);
            ax1 += __low2float(v1); ay1 += __high2float(v1);
        }
        if (n < e) {
            __half2 v0 = h2[(size_t)n * HP2 + lane];
            ax0 += __low2float(v0); ay0 += __high2float(v0);
        }
        red[w][lane][0] = ax0 + ax1;
        red[w][lane][1] = ay0 + ay1;
    }
    __syncthreads();
    if (tid < F2) {
        pooled[2 * tid]     = red[0][tid][0] + red[1][tid][0] + red[2][tid][0] + red[3][tid][0];
        pooled[2 * tid + 1] = red[0][tid][1] + red[1][tid][1] + red[2][tid][1] + red[3][tid][1];
    }
    __syncthreads();
    if (tid < OD) {
        float acc = blin[tid];
        #pragma unroll 8
        for (int f = 0; f < MD; ++f)
            acc = fmaf(pooled[f], Wlin[f * OD + tid], acc);
        out[(size_t)g * OD + tid] = acc;
    }
}

// ---------------- launch ----------------

extern "C" void kernel_launch(void* const* d_in, const int* in_sizes, int n_in,
                              void* d_out, int out_size, void* d_ws, size_t ws_size,
                              hipStream_t stream) {
    const float* x     = (const float*)d_in[0];
    const int*   edge  = (const int*)d_in[1];
    const int*   batch = (const int*)d_in[2];
    const float* W1l = (const float*)d_in[3];
    const float* W1r = (const float*)d_in[4];
    const float* b1  = (const float*)d_in[5];
    const float* W2l = (const float*)d_in[6];
    const float* W2r = (const float*)d_in[7];
    const float* b2  = (const float*)d_in[8];
    const float* W3l = (const float*)d_in[9];
    const float* W3r = (const float*)d_in[10];
    const float* b3  = (const float*)d_in[11];
    const float* Wlin = (const float*)d_in[12];
    const float* blin = (const float*)d_in[13];
    float* out = (float*)d_out;

    const int N = in_sizes[0] / CF;     // 50000
    const int E = in_sizes[1] / 2;      // 800000

    char* ws = (char*)d_ws;
    auto alloc = [&](size_t bytes) -> void* {
        void* p = (void*)ws;
        ws += (bytes + 255) & ~(size_t)255;
        return p;
    };
    int*       sbcur   = (int*)alloc((size_t)NSB * 4);
    unsigned*  sbrec   = (unsigned*)alloc((size_t)NSB * SBCAP * 4);
    int*       csr     = (int*)alloc((size_t)NSB * SBCAP * 4);
    int2*      off2    = (int2*)alloc((size_t)N * 8);
    _Float16*  Wct1    = (_Float16*)alloc((size_t)176 * K1P * 2);
    _Float16*  Wct23   = (_Float16*)alloc((size_t)2 * 176 * HP * 2);
    _Float16*  xh      = (_Float16*)alloc((size_t)N * K1P * 2);
    _Float16*  yl      = (_Float16*)alloc((size_t)N * YLS * 2);
    _Float16*  yr      = (_Float16*)alloc((size_t)N * MD * 2);
    _Float16*  h       = (_Float16*)alloc((size_t)N * HP * 2);

    hipMemsetAsync(sbcur, 0, (size_t)NSB * 4, stream);
    bin_kernel<<<(E + TILE - 1) / TILE, 256, 0, stream>>>(edge, E, sbcur, sbrec);
    csr256_kernel<<<NSB, 256, 0, stream>>>(sbrec, sbcur, csr, off2, N);

    convx_kernel<<<(N * K1P + 255) / 256, 256, 0, stream>>>(x, xh, N);
    build_wct_all<<<(176 * K1P + 2 * 176 * HP + 255) / 256, 256, 0, stream>>>(
        W1l, W1r, W2l, W2r, W3l, W3r, Wct1, Wct23);

    const int gemm_blocks = (N + 127) / 128;
    const int agg_blocks  = (N * NCH + 255) / 256;

    // layer 1 (K=108, KPAD=128)
    gemm_mfma_kernel<K1P><<<gemm_blocks, 256, 0, stream>>>(xh, Wct1, b1, yl, yr, N);
    agg_kernel<<<agg_blocks, 256, 0, stream>>>(yl, yr, off2, csr, h, N);

    // layer 2 (K=88, KPAD=96)
    gemm_mfma_kernel<HP><<<gemm_blocks, 256, 0, stream>>>(h, Wct23, b2, yl, yr, N);
    agg_kernel<<<agg_blocks, 256, 0, stream>>>(yl, yr, off2, csr, h, N);

    // layer 3 (K=88, KPAD=96)
    gemm_mfma_kernel<HP><<<gemm_blocks, 256, 0, stream>>>(h, Wct23 + (size_t)176 * HP, b3, yl, yr, N);
    agg_kernel<<<agg_blocks, 256, 0, stream>>>(yl, yr, off2, csr, h, N);

    // fused pool + classifier
    pool_final_kernel<<<NG, 256, 0, stream>>>((const __half2*)h, batch, Wlin, blin, out, N);
}

// Round 13
// 203.001 us; speedup vs baseline: 8.2195x; 1.0313x over previous
//
#include <hip/hip_runtime.h>
#include <hip/hip_fp16.h>

#define NN 50000
#define NG 256
#define CF 108
#define MD 88
#define OD 100
#define F2 44    // half2 per 88-feat row
#define HP 96    // h row stride in halfs (88 + 8 zero pad, MFMA K=96)
#define HP2 48   // h row stride in half2
#define YLS 96   // yl row stride in halfs (192B: rows span exactly 2x128B lines)
#define K1P 128  // layer-1 K padded (108 -> 128)
#define NSB 196      // super-buckets of 256 nodes
#define SBCAP 5120   // records per super-bucket (avg 4096)
#define TILE 2048    // edges per bin block
#define NCH 12       // 16B chunks per node in agg (11 real + 1 pad)

typedef _Float16 f16x8 __attribute__((ext_vector_type(8)));
typedef float f32x4 __attribute__((ext_vector_type(4)));

// ---------------- fused prep: binning | convx | weight transpose ----------------

__global__ __launch_bounds__(256) void prep_kernel(const int* __restrict__ edge, int E,
                                                   int* __restrict__ sbcur,
                                                   unsigned* __restrict__ sbrec,
                                                   const float* __restrict__ x,
                                                   _Float16* __restrict__ xh, int N,
                                                   const float* __restrict__ W1l, const float* __restrict__ W1r,
                                                   const float* __restrict__ W2l, const float* __restrict__ W2r,
                                                   const float* __restrict__ W3l, const float* __restrict__ W3r,
                                                   _Float16* __restrict__ Wct1, _Float16* __restrict__ Wct23,
                                                   int nbin, int nconvx) {
    const int tid = threadIdx.x;
    const int bb  = blockIdx.x;

    if (bb < nbin) {
        // ---- binning: record = (src<<8)|(dst&255), bin = dst>>8
        __shared__ int bcnt[NSB], boff[NSB], bfill[NSB], gbase[NSB];
        __shared__ int sc[256];
        __shared__ unsigned stag[TILE];
        __shared__ unsigned char stagbin[TILE];
        const int t0  = bb * TILE;
        const int tcnt = min(TILE, E - t0);

        for (int i = tid; i < NSB; i += 256) bcnt[i] = 0;
        __syncthreads();

        unsigned recs[TILE / 256];
        int      bins[TILE / 256];
        #pragma unroll
        for (int j = 0; j < TILE / 256; ++j) {
            const int e = t0 + j * 256 + tid;
            bins[j] = -1;
            if (e < E) {
                const int dst = edge[E + e], src = edge[e];
                bins[j] = dst >> 8;
                recs[j] = ((unsigned)src << 8) | (unsigned)(dst & 255);
                atomicAdd(&bcnt[bins[j]], 1);
            }
        }
        __syncthreads();

        sc[tid] = (tid < NSB) ? bcnt[tid] : 0;
        __syncthreads();
        for (int d = 1; d < 256; d <<= 1) {
            int v = (tid >= d) ? sc[tid - d] : 0;
            __syncthreads();
            sc[tid] += v;
            __syncthreads();
        }
        if (tid < NSB) {
            boff[tid]  = sc[tid] - bcnt[tid];
            bfill[tid] = sc[tid] - bcnt[tid];
            if (bcnt[tid] > 0) gbase[tid] = atomicAdd(&sbcur[tid], bcnt[tid]);
        }
        __syncthreads();

        #pragma unroll
        for (int j = 0; j < TILE / 256; ++j) {
            if (bins[j] >= 0) {
                int pos = atomicAdd(&bfill[bins[j]], 1);
                stag[pos]    = recs[j];
                stagbin[pos] = (unsigned char)bins[j];
            }
        }
        __syncthreads();

        for (int i = tid; i < tcnt; i += 256) {
            const int b   = stagbin[i];
            const int rel = i - boff[b];
            const int gp  = gbase[b] + rel;
            if (gp < SBCAP) sbrec[(size_t)b * SBCAP + gp] = stag[i];
        }
    } else if (bb < nbin + nconvx) {
        // ---- x -> f16 padded [N][128]
        const int i = (bb - nbin) * 256 + tid;
        if (i < N * K1P) {
            int n = i >> 7, k = i & (K1P - 1);
            xh[i] = (k < CF) ? (_Float16)x[n * CF + k] : (_Float16)0.f;
        }
    } else {
        // ---- transposed combined weights
        const int n1 = 176 * K1P;
        const int n2 = 176 * HP;
        const int idx = (bb - nbin - nconvx) * 256 + tid;
        if (idx < n1) {
            int c = idx / K1P, k = idx - c * K1P;
            float v = (k < CF) ? ((c < MD) ? W1l[k * MD + c] : W1r[k * MD + (c - MD)]) : 0.f;
            Wct1[idx] = (_Float16)v;
        } else if (idx < n1 + 2 * n2) {
            int j = idx - n1;
            const float* Wl = (j < n2) ? W2l : W3l;
            const float* Wr = (j < n2) ? W2r : W3r;
            int jj = (j < n2) ? j : j - n2;
            int c = jj / HP, k = jj - c * HP;
            float v = (k < MD) ? ((c < MD) ? Wl[k * MD + c] : Wr[k * MD + (c - MD)]) : 0.f;
            Wct23[j] = (_Float16)v;
        }
    }
}

// ---------------- per-super-bucket CSR + degree-sorted order ----------------

__global__ __launch_bounds__(256) void csr256_kernel(const unsigned* __restrict__ sbrec,
                                                     const int* __restrict__ sbcur,
                                                     int* __restrict__ csr,
                                                     int2* __restrict__ off2,
                                                     int* __restrict__ order, int N) {
    __shared__ int hist[256], base[256], offc[256], sc[256];
    __shared__ int dcnt[64], dpos[64];
    const int b = blockIdx.x, tid = threadIdx.x;
    const int cnt = min(sbcur[b], SBCAP);
    const unsigned* rec = sbrec + (size_t)b * SBCAP;

    hist[tid] = 0;
    if (tid < 64) dcnt[tid] = 0;
    __syncthreads();
    for (int r = tid; r < cnt; r += 256) atomicAdd(&hist[rec[r] & 255u], 1);
    __syncthreads();

    sc[tid] = hist[tid];
    __syncthreads();
    for (int d = 1; d < 256; d <<= 1) {
        int v = (tid >= d) ? sc[tid - d] : 0;
        __syncthreads();
        sc[tid] += v;
        __syncthreads();
    }
    base[tid] = sc[tid] - hist[tid];
    offc[tid] = base[tid];
    __syncthreads();

    for (int r = tid; r < cnt; r += 256) {
        const unsigned u = rec[r];
        const int dl = (int)(u & 255u);
        const int pos = atomicAdd(&offc[dl], 1);
        csr[(size_t)b * SBCAP + pos] = (int)(u >> 8);
    }

    // ---- degree counting-sort -> order[] (deg-homogeneous waves in agg)
    const int n = b * 256 + tid;
    const int deg = (n < N) ? min(hist[tid], 63) : 63;   // invalid nodes cluster at end
    atomicAdd(&dcnt[deg], 1);
    __syncthreads();
    if (tid < 64) {
        int v = dcnt[tid];
        int incl = v;
        #pragma unroll
        for (int s = 1; s < 64; s <<= 1) {
            int t = __shfl_up(incl, s, 64);
            if (tid >= s) incl += t;
        }
        dpos[tid] = incl - v;
    }
    __syncthreads();
    const int rank = atomicAdd(&dpos[deg], 1);
    order[b * 256 + rank] = (n < N) ? n : -1;

    if (n < N) off2[n] = make_int2(b * SBCAP + base[tid], hist[tid]);
}

// ---------------- MFMA GEMM: 128 rows/block, 2 row-tiles per wave (B reuse) ----------------

template <int KPAD>
__global__ __launch_bounds__(256) void gemm_mfma_kernel(const _Float16* __restrict__ Ah,
                                                        const _Float16* __restrict__ Wct,
                                                        const float* __restrict__ bias,
                                                        _Float16* __restrict__ yl,
                                                        _Float16* __restrict__ yr, int N) {
    const int wave = threadIdx.x >> 6;
    const int lane = threadIdx.x & 63;
    const int r16  = lane & 15;
    const int kg   = lane >> 4;
    const int rbase = blockIdx.x * 128 + wave * 16;

    const int arow0 = min(rbase + r16, N - 1);
    const int arow1 = min(rbase + 64 + r16, N - 1);
    const _Float16* ap0 = Ah + (size_t)arow0 * KPAD + kg * 8;
    const _Float16* ap1 = Ah + (size_t)arow1 * KPAD + kg * 8;

    f32x4 acc[2][11];
    #pragma unroll
    for (int q = 0; q < 2; ++q)
        #pragma unroll
        for (int t = 0; t < 11; ++t) acc[q][t] = (f32x4){0.f, 0.f, 0.f, 0.f};

    #pragma unroll
    for (int ks = 0; ks < KPAD / 32; ++ks) {
        f16x8 af0 = *(const f16x8*)(ap0 + ks * 32);
        f16x8 af1 = *(const f16x8*)(ap1 + ks * 32);
        #pragma unroll
        for (int t = 0; t < 11; ++t) {
            const _Float16* bp = Wct + (size_t)(t * 16 + r16) * KPAD + ks * 32 + kg * 8;
            f16x8 bf = *(const f16x8*)bp;
            acc[0][t] = __builtin_amdgcn_mfma_f32_16x16x32_f16(af0, bf, acc[0][t], 0, 0, 0);
            acc[1][t] = __builtin_amdgcn_mfma_f32_16x16x32_f16(af1, bf, acc[1][t], 0, 0, 0);
        }
    }

    #pragma unroll
    for (int q = 0; q < 2; ++q) {
        const int orow0 = rbase + q * 64 + kg * 4;
        #pragma unroll
        for (int t = 0; t < 11; ++t) {
            const int c = t * 16 + r16;
            const bool isr = (c >= MD);
            const float bv = isr ? bias[c - MD] : 0.f;
            _Float16* dst = isr ? (yr + (c - MD)) : (yl + c);
            const int st = isr ? MD : YLS;
            #pragma unroll
            for (int r = 0; r < 4; ++r) {
                const int row = orow0 + r;
                if (row < N) dst[(size_t)row * st] = (_Float16)(acc[q][t][r] + bv);
            }
        }
    }
}

// ---------------- fused aggregate: 16B gathers, deg-sorted node order ----------------

__global__ void agg_kernel(const _Float16* __restrict__ yl, const _Float16* __restrict__ yr,
                           const int2* __restrict__ off2, const int* __restrict__ csr,
                           const int* __restrict__ order,
                           _Float16* __restrict__ h, int total) {
    int idx = blockIdx.x * blockDim.x + threadIdx.x;
    if (idx >= total) return;
    int slot = idx / NCH;
    int c = idx - slot * NCH;
    const int n = order[slot];
    if (n < 0) return;
    if (c >= 11) {
        *(f16x8*)(h + (size_t)n * HP + 88) = (f16x8)(_Float16)0.f;
        return;
    }
    const int2 o = off2[n];
    const int s = o.x, e = o.x + o.y;
    float a0[8] = {0,0,0,0,0,0,0,0}, a1[8] = {0,0,0,0,0,0,0,0};
    float a2[8] = {0,0,0,0,0,0,0,0}, a3[8] = {0,0,0,0,0,0,0,0};
    const size_t cof = (size_t)c * 8;
    int i = s;
    for (; i + 7 < e; i += 8) {
        f16x8 v0 = *(const f16x8*)(yl + (size_t)csr[i]     * YLS + cof);
        f16x8 v1 = *(const f16x8*)(yl + (size_t)csr[i + 1] * YLS + cof);
        f16x8 v2 = *(const f16x8*)(yl + (size_t)csr[i + 2] * YLS + cof);
        f16x8 v3 = *(const f16x8*)(yl + (size_t)csr[i + 3] * YLS + cof);
        f16x8 v4 = *(const f16x8*)(yl + (size_t)csr[i + 4] * YLS + cof);
        f16x8 v5 = *(const f16x8*)(yl + (size_t)csr[i + 5] * YLS + cof);
        f16x8 v6 = *(const f16x8*)(yl + (size_t)csr[i + 6] * YLS + cof);
        f16x8 v7 = *(const f16x8*)(yl + (size_t)csr[i + 7] * YLS + cof);
        #pragma unroll
        for (int j = 0; j < 8; ++j) {
            a0[j] += (float)v0[j] + (float)v1[j];
            a1[j] += (float)v2[j] + (float)v3[j];
            a2[j] += (float)v4[j] + (float)v5[j];
            a3[j] += (float)v6[j] + (float)v7[j];
        }
    }
    for (; i + 1 < e; i += 2) {
        f16x8 v0 = *(const f16x8*)(yl + (size_t)csr[i]     * YLS + cof);
        f16x8 v1 = *(const f16x8*)(yl + (size_t)csr[i + 1] * YLS + cof);
        #pragma unroll
        for (int j = 0; j < 8; ++j) {
            a0[j] += (float)v0[j];
            a1[j] += (float)v1[j];
        }
    }
    if (i < e) {
        f16x8 v0 = *(const f16x8*)(yl + (size_t)csr[i] * YLS + cof);
        #pragma unroll
        for (int j = 0; j < 8; ++j) a0[j] += (float)v0[j];
    }
    const float inv = 1.0f / (float)max(o.y, 1);
    const f16x8 r = *(const f16x8*)(yr + (size_t)n * MD + cof);
    f16x8 outv;
    #pragma unroll
    for (int j = 0; j < 8; ++j) {
        float v = (a0[j] + a1[j] + a2[j] + a3[j]) * inv + (float)r[j];
        outv[j] = (_Float16)fmaxf(v, 0.f);
    }
    *(f16x8*)(h + (size_t)n * HP + cof) = outv;
}

// ---------------- fused pool + classifier: block per graph ----------------

__global__ __launch_bounds__(256) void pool_final_kernel(const __half2* __restrict__ h2,
                                                         const int* __restrict__ batch,
                                                         const float* __restrict__ Wlin,
                                                         const float* __restrict__ blin,
                                                         float* __restrict__ out, int N) {
    __shared__ float red[4][F2][2];
    __shared__ float pooled[MD];
    __shared__ int range[2];
    const int g    = blockIdx.x;
    const int tid  = threadIdx.x;
    const int w    = tid >> 6;
    const int lane = tid & 63;

    if (tid < 2) {
        const int tgt = g + tid;
        int lo = 0, hi = N;
        while (lo < hi) {
            int mid = (lo + hi) >> 1;
            if (batch[mid] < tgt) lo = mid + 1; else hi = mid;
        }
        range[tid] = lo;
    }
    __syncthreads();
    const int s = range[0], e = range[1];

    float ax0 = 0.f, ay0 = 0.f, ax1 = 0.f, ay1 = 0.f;
    if (lane < F2) {
        int n = s + w;
        for (; n + 4 < e; n += 8) {
            __half2 v0 = h2[(size_t)n * HP2 + lane];
            __half2 v1 = h2[(size_t)(n + 4) * HP2 + lane];
            ax0 += __low2float(v0); ay0 += __high2float(v0);
            ax1 += __low2float(v1); ay1 += __high2float(v1);
        }
        if (n < e) {
            __half2 v0 = h2[(size_t)n * HP2 + lane];
            ax0 += __low2float(v0); ay0 += __high2float(v0);
        }
        red[w][lane][0] = ax0 + ax1;
        red[w][lane][1] = ay0 + ay1;
    }
    __syncthreads();
    if (tid < F2) {
        pooled[2 * tid]     = red[0][tid][0] + red[1][tid][0] + red[2][tid][0] + red[3][tid][0];
        pooled[2 * tid + 1] = red[0][tid][1] + red[1][tid][1] + red[2][tid][1] + red[3][tid][1];
    }
    __syncthreads();
    if (tid < OD) {
        float acc = blin[tid];
        #pragma unroll 8
        for (int f = 0; f < MD; ++f)
            acc = fmaf(pooled[f], Wlin[f * OD + tid], acc);
        out[(size_t)g * OD + tid] = acc;
    }
}

// ---------------- launch ----------------

extern "C" void kernel_launch(void* const* d_in, const int* in_sizes, int n_in,
                              void* d_out, int out_size, void* d_ws, size_t ws_size,
                              hipStream_t stream) {
    const float* x     = (const float*)d_in[0];
    const int*   edge  = (const int*)d_in[1];
    const int*   batch = (const int*)d_in[2];
    const float* W1l = (const float*)d_in[3];
    const float* W1r = (const float*)d_in[4];
    const float* b1  = (const float*)d_in[5];
    const float* W2l = (const float*)d_in[6];
    const float* W2r = (const float*)d_in[7];
    const float* b2  = (const float*)d_in[8];
    const float* W3l = (const float*)d_in[9];
    const float* W3r = (const float*)d_in[10];
    const float* b3  = (const float*)d_in[11];
    const float* Wlin = (const float*)d_in[12];
    const float* blin = (const float*)d_in[13];
    float* out = (float*)d_out;

    const int N = in_sizes[0] / CF;     // 50000
    const int E = in_sizes[1] / 2;      // 800000

    char* ws = (char*)d_ws;
    auto alloc = [&](size_t bytes) -> void* {
        void* p = (void*)ws;
        ws += (bytes + 255) & ~(size_t)255;
        return p;
    };
    int*       sbcur   = (int*)alloc((size_t)NSB * 4);
    unsigned*  sbrec   = (unsigned*)alloc((size_t)NSB * SBCAP * 4);
    int*       csr     = (int*)alloc((size_t)NSB * SBCAP * 4);
    int2*      off2    = (int2*)alloc((size_t)N * 8);
    int*       order   = (int*)alloc((size_t)NSB * 256 * 4);
    _Float16*  Wct1    = (_Float16*)alloc((size_t)176 * K1P * 2);
    _Float16*  Wct23   = (_Float16*)alloc((size_t)2 * 176 * HP * 2);
    _Float16*  xh      = (_Float16*)alloc((size_t)N * K1P * 2);
    _Float16*  yl      = (_Float16*)alloc((size_t)N * YLS * 2);
    _Float16*  yr      = (_Float16*)alloc((size_t)N * MD * 2);
    _Float16*  h       = (_Float16*)alloc((size_t)N * HP * 2);

    const int nbin   = (E + TILE - 1) / TILE;
    const int nconvx = (N * K1P + 255) / 256;
    const int nwct   = (176 * K1P + 2 * 176 * HP + 255) / 256;

    hipMemsetAsync(sbcur, 0, (size_t)NSB * 4, stream);
    prep_kernel<<<nbin + nconvx + nwct, 256, 0, stream>>>(
        edge, E, sbcur, sbrec, x, xh, N,
        W1l, W1r, W2l, W2r, W3l, W3r, Wct1, Wct23, nbin, nconvx);
    csr256_kernel<<<NSB, 256, 0, stream>>>(sbrec, sbcur, csr, off2, order, N);

    const int gemm_blocks = (N + 127) / 128;
    const int agg_total   = NSB * 256 * NCH;
    const int agg_blocks  = (agg_total + 255) / 256;

    // layer 1 (K=108, KPAD=128)
    gemm_mfma_kernel<K1P><<<gemm_blocks, 256, 0, stream>>>(xh, Wct1, b1, yl, yr, N);
    agg_kernel<<<agg_blocks, 256, 0, stream>>>(yl, yr, off2, csr, order, h, agg_total);

    // layer 2 (K=88, KPAD=96)
    gemm_mfma_kernel<HP><<<gemm_blocks, 256, 0, stream>>>(h, Wct23, b2, yl, yr, N);
    agg_kernel<<<agg_blocks, 256, 0, stream>>>(yl, yr, off2, csr, order, h, agg_total);

    // layer 3 (K=88, KPAD=96)
    gemm_mfma_kernel<HP><<<gemm_blocks, 256, 0, stream>>>(h, Wct23 + (size_t)176 * HP, b3, yl, yr, N);
    agg_kernel<<<agg_blocks, 256, 0, stream>>>(yl, yr, off2, csr, order, h, agg_total);

    // fused pool + classifier
    pool_final_kernel<<<NG, 256, 0, stream>>>((const __half2*)h, batch, Wlin, blin, out, N);
}